// Round 20
// baseline (547.121 us; speedup 1.0000x reference)
//
#include <hip/hip_runtime.h>
#include <math.h>

#define NPTS 2048
#define PPB  131072   // positions per batch = 2048 * 64

typedef __attribute__((ext_vector_type(8))) short bf8_t;   // 8 bf16 (4 VGPRs)
typedef __attribute__((ext_vector_type(4))) float f4_t;    // MFMA accumulator

__device__ __forceinline__ unsigned short f2bf(float x) {
  unsigned u = __float_as_uint(x);
  u += 0x7FFFu + ((u >> 16) & 1u);          // RNE
  return (unsigned short)(u >> 16);
}
__device__ __forceinline__ float bf2f(unsigned short h) {
  return __uint_as_float(((unsigned)h) << 16);
}
// 2 f32 -> packed 2xbf16 in one VALU op (low half = a, high half = b; RNE)
__device__ __forceinline__ unsigned cvt_pk_bf16(float a, float b) {
  unsigned r;
  asm("v_cvt_pk_bf16_f32 %0, %1, %2" : "=v"(r) : "v"(a), "v"(b));
  return r;
}

// ---------------------------------------------------------------- angle ----
__device__ __forceinline__ float angle_f(float ax, float ay, float az,
                                         float bx, float by, float bz) {
  float cx = ay * bz - az * by;
  float cy = az * bx - ax * bz;
  float cz = ax * by - ay * bx;
  float cn = cx * cx + cy * cy + cz * cz;
  float dt = ax * bx + ay * by + az * bz;
  bool  sml = cn < 1e-20f;
  bool  deg = sml && (fabsf(dt) < 1e-12f);
  float cns = sml ? 0.0f : sqrtf(cn);
  float ang = atan2f(cns, dt);
  return deg ? 0.0f : ang;
}

// --------------- weight prep: bf16 frags for conv1/2/3 and post1/2 --------
__global__ __launch_bounds__(256) void k_wprep(
    const float* __restrict__ w1, const float* __restrict__ w2,
    const float* __restrict__ w3, const float* __restrict__ w4,
    const float* __restrict__ w5,
    unsigned short* __restrict__ wh1, unsigned short* __restrict__ wh2,
    unsigned short* __restrict__ wh3, unsigned short* __restrict__ wh4,
    unsigned short* __restrict__ wh5) {
  int t = blockIdx.x * 256 + threadIdx.x;
  if (t < 3072) {            // conv1: 1 ks * 6 nt (96x10, K padded to 32)
    int i = t & 7, lane = (t >> 3) & 63, nt = t >> 9;
    int k = ((lane >> 4) << 3) + i;
    int n = nt * 16 + (lane & 15);
    wh1[t] = (k < 10) ? f2bf(w1[n * 10 + k]) : (unsigned short)0;
  } else if (t < 12288) {    // conv2: 3 ks * 6 nt (96x96)
    int f = t - 3072;
    int i = f & 7, lane = (f >> 3) & 63, r = f >> 9, nt = r % 6, ks = r / 6;
    int k = ks * 32 + ((lane >> 4) << 3) + i;
    int n = nt * 16 + (lane & 15);
    wh2[f] = f2bf(w2[n * 96 + k]);
  } else if (t < 30720) {    // conv3: 3 ks * 12 nt (192x96)
    int f = t - 12288;
    int i = f & 7, lane = (f >> 3) & 63, r = f >> 9, nt = r % 12, ks = r / 12;
    int k = ks * 32 + ((lane >> 4) << 3) + i;
    int n = nt * 16 + (lane & 15);
    wh3[f] = f2bf(w3[n * 96 + k]);
  } else if (t < 67584) {    // post1: 6 ks * 12 nt (192x192)
    int f = t - 30720;
    int i = f & 7, lane = (f >> 3) & 63, r = f >> 9, nt = r % 12, ks = r / 12;
    int k = ks * 32 + ((lane >> 4) << 3) + i;
    int n = nt * 16 + (lane & 15);
    wh4[f] = f2bf(w4[n * 192 + k]);
  } else if (t < 86016) {    // post2: 6 ks * 6 nt (96x192)
    int f = t - 67584;
    int i = f & 7, lane = (f >> 3) & 63, r = f >> 9, nt = r % 6, ks = r / 6;
    int k = ks * 32 + ((lane >> 4) << 3) + i;
    int n = nt * 16 + (lane & 15);
    wh5[f] = f2bf(w5[n * 192 + k]);
  }
}

// ---------------------------------------------------- K1: neighbors+feat ----
__global__ __launch_bounds__(256) void k_feat(
    const float* __restrict__ xyz, const float* __restrict__ nrm,
    const float* __restrict__ w1, const float* __restrict__ b1,
    unsigned short* __restrict__ fused, float* __restrict__ st) {
  const int wid = threadIdx.x >> 6, lane = threadIdx.x & 63;
  const int b = blockIdx.x >> 9;
  const int n = ((blockIdx.x & 511) << 2) + wid;
  const float* X  = xyz + (size_t)b * NPTS * 3;
  const float* NR = nrm + (size_t)b * NPTS * 3;
  __shared__ int   lst[4][64];
  __shared__ float red[16];

  const float xi0 = X[n * 3 + 0], xi1 = X[n * 3 + 1], xi2 = X[n * 3 + 2];

  int cnt = 0;
  for (int jb = 0; jb < NPTS; jb += 64) {
    int   j  = jb + lane;
    float dx = __fsub_rn(xi0, X[j * 3 + 0]);
    float dy = __fsub_rn(xi1, X[j * 3 + 1]);
    float dz = __fsub_rn(xi2, X[j * 3 + 2]);
    float sq = __fadd_rn(__fadd_rn(__fmul_rn(dx, dx), __fmul_rn(dy, dy)),
                         __fmul_rn(dz, dz));
    bool act = (sq <= 0.09f);
    unsigned long long m = __ballot(act);
    int pos = cnt + __popcll(m & ((1ull << lane) - 1ull));
    if (act && pos < 64) lst[wid][pos] = j;
    cnt += __popcll(m);
    if (cnt >= 64) break;
  }
  __syncthreads();

  const int j = lst[wid][(lane < cnt) ? lane : 0];

  const float gx = X[j * 3 + 0],  gy = X[j * 3 + 1],  gz = X[j * 3 + 2];
  const float gnx = NR[j * 3 + 0], gny = NR[j * 3 + 1], gnz = NR[j * 3 + 2];
  const float nix = NR[n * 3 + 0], niy = NR[n * 3 + 1], niz = NR[n * 3 + 2];
  const float dx = gx - xi0, dy = gy - xi1, dz = gz - xi2;

  float f[10];
  f[0] = xi0; f[1] = xi1; f[2] = xi2;
  f[3] = dx;  f[4] = dy;  f[5] = dz;
  f[6] = angle_f(nix, niy, niz, dx, dy, dz);
  f[7] = angle_f(gnx, gny, gnz, dx, dy, dz);
  f[8] = angle_f(nix, niy, niz, gnx, gny, gnz);
  float ss = dx * dx + dy * dy + dz * dz;
  f[9] = (ss < 1e-20f) ? 0.0f : sqrtf(ss);

  size_t base = (size_t)b * 10 * PPB + (size_t)n * 64 + lane;
#pragma unroll
  for (int c = 0; c < 10; ++c) fused[base + (size_t)c * PPB] = f2bf(f[c]);

  float sg[8], qg[8];
#pragma unroll
  for (int g = 0; g < 8; ++g) {
    float s = 0.f, q = 0.f;
#pragma unroll
    for (int t2 = 0; t2 < 12; ++t2) {
      const int o = g * 12 + t2;
      float a = b1[o];
#pragma unroll
      for (int c = 0; c < 10; ++c) a += w1[o * 10 + c] * f[c];
      s += a; q += a * a;
    }
    sg[g] = s; qg[g] = q;
  }
#pragma unroll
  for (int g = 0; g < 8; ++g) {
#pragma unroll
    for (int off = 32; off; off >>= 1) {
      sg[g] += __shfl_xor(sg[g], off);
      qg[g] += __shfl_xor(qg[g], off);
    }
  }
  if (threadIdx.x < 16) red[threadIdx.x] = 0.f;
  __syncthreads();
  if (lane == 0) {
#pragma unroll
    for (int g = 0; g < 8; ++g) {
      atomicAdd(&red[2 * g + 0], sg[g]);
      atomicAdd(&red[2 * g + 1], qg[g]);
    }
  }
  __syncthreads();
  if (threadIdx.x < 16) atomicAdd(&st[b * 16 + threadIdx.x], red[threadIdx.x]);
}

// ---------------------- K_gram: conv1 (MFMA) -> x1, G = sum x1~ x1~^T ------
#define GRAM_TILE(i, MT, NT) \
  acc[i] = __builtin_amdgcn_mfma_f32_16x16x32_bf16(fh##MT, fh##NT, acc[i], 0, 0, 0);
#define GRAM_LD(T) \
  bf8_t fh##T = *(const bf8_t*)&x1h[pp][T * 16 + l15][ko];
#define GRAM_OUT(i, MT, NT) do { \
  _Pragma("unroll") \
  for (int r = 0; r < 4; ++r) \
    atomicAdd(&Gb[(MT * 16 + q * 4 + r) * 112 + NT * 16 + l15], acc[i][r]); \
} while (0)

__global__ __launch_bounds__(256) void k_gram(
    const unsigned short* __restrict__ fused, const unsigned short* __restrict__ wh1,
    const float* __restrict__ b1, const float* __restrict__ st1g,
    const float* __restrict__ g1, const float* __restrict__ be1,
    float* __restrict__ G) {
  __shared__ unsigned short x1h[2][112][72];
  __shared__ unsigned short x0bf[128][40];   // bf16 x0, K-padded (2 points)
  __shared__ float A1s[96], B1s[96], b1s[96];
  const int t = threadIdx.x, lane = t & 63, w = t >> 6;
  const int l15 = lane & 15, q = lane >> 4;
  const int b = blockIdx.x >> 6;          // 512 blocks = 8 batches x 64
  const int blk = blockIdx.x & 63;        // 32 points each (16 iters x 2)

  if (t < 96) {   // fused fin1
    int g = t / 12;
    float s = st1g[b * 16 + 2 * g], qq = st1g[b * 16 + 2 * g + 1];
    float mean = s * (1.0f / 1572864.0f);
    float var  = qq * (1.0f / 1572864.0f) - mean * mean;
    float r    = 1.0f / sqrtf(var + 1e-5f);
    float a    = g1[t] * r;
    A1s[t] = a; B1s[t] = be1[t] - mean * a; b1s[t] = b1[t];
  }
  for (int idx = t; idx < 2 * 16 * 72; idx += 256) {  // ones row 96, zeros 97..111
    int pp = idx / (16 * 72), rem = idx % (16 * 72);
    int ch = 96 + rem / 72, rr = rem % 72;
    x1h[pp][ch][rr] = (ch == 96) ? (unsigned short)0x3F80 : (unsigned short)0;
  }
  __syncthreads();

  f4_t acc[7];
#pragma unroll
  for (int i = 0; i < 7; ++i) acc[i] = (f4_t){0.f, 0.f, 0.f, 0.f};

  for (int it = 0; it < 16; ++it) {
    int n = blk * 32 + it * 2;
    size_t fb = (size_t)b * 10 * PPB + (size_t)n * 64;
    __syncthreads();   // prior Gram reads done before overwrite
    for (int idx = t; idx < 128 * 11; idx += 256) {  // zero cols 10..31
      int R = idx / 11, u = 5 + idx % 11;
      *(unsigned*)&x0bf[R][u * 2] = 0u;
    }
    for (int idx = t; idx < 1280; idx += 256) {      // fill cols 0..9 (2 pts)
      int c = idx >> 7, s = idx & 127;
      x0bf[s][c] = fused[fb + (size_t)c * PPB + s];
    }
    __syncthreads();
    // conv1 via MFMA for both points: wave w owns rows w*16..w*16+15 of each
#pragma unroll
    for (int pp = 0; pp < 2; ++pp) {
      bf8_t af0 = *(const bf8_t*)&x0bf[pp * 64 + w * 16 + l15][q * 8];
#pragma unroll
      for (int nt = 0; nt < 6; ++nt) {
        f4_t a1c = (f4_t){0.f, 0.f, 0.f, 0.f};
        bf8_t bh = *(const bf8_t*)(wh1 + (((nt << 6) + lane) << 3));
        a1c = __builtin_amdgcn_mfma_f32_16x16x32_bf16(af0, bh, a1c, 0, 0, 0);
        const int ch = nt * 16 + l15;
        const float A = A1s[ch], Bb = B1s[ch], bi = b1s[ch];
#pragma unroll
        for (int r = 0; r < 4; ++r) {
          float x = A * (a1c[r] + bi) + Bb;
          x1h[pp][ch][w * 16 + q * 4 + r] = f2bf(x > 0.f ? x : 0.f);
        }
      }
    }
    __syncthreads();
#pragma unroll
    for (int pp = 0; pp < 2; ++pp) {
#pragma unroll
      for (int ksr = 0; ksr < 2; ++ksr) {
        const int ko = ksr * 32 + q * 8;
        GRAM_LD(0) GRAM_LD(1) GRAM_LD(2) GRAM_LD(3) GRAM_LD(4) GRAM_LD(5) GRAM_LD(6)
        if (w == 0) {
          GRAM_TILE(0, 0, 0); GRAM_TILE(1, 0, 1); GRAM_TILE(2, 0, 2);
          GRAM_TILE(3, 0, 3); GRAM_TILE(4, 0, 4); GRAM_TILE(5, 0, 5); GRAM_TILE(6, 0, 6);
        } else if (w == 1) {
          GRAM_TILE(0, 1, 1); GRAM_TILE(1, 1, 2); GRAM_TILE(2, 1, 3);
          GRAM_TILE(3, 1, 4); GRAM_TILE(4, 1, 5); GRAM_TILE(5, 1, 6); GRAM_TILE(6, 2, 2);
        } else if (w == 2) {
          GRAM_TILE(0, 2, 3); GRAM_TILE(1, 2, 4); GRAM_TILE(2, 2, 5);
          GRAM_TILE(3, 2, 6); GRAM_TILE(4, 3, 3); GRAM_TILE(5, 3, 4); GRAM_TILE(6, 3, 5);
        } else {
          GRAM_TILE(0, 3, 6); GRAM_TILE(1, 4, 4); GRAM_TILE(2, 4, 5);
          GRAM_TILE(3, 4, 6); GRAM_TILE(4, 5, 5); GRAM_TILE(5, 5, 6); GRAM_TILE(6, 6, 6);
        }
      }
    }
  }
  float* Gb = G + (size_t)b * 12544;
  if (w == 0) {
    GRAM_OUT(0, 0, 0); GRAM_OUT(1, 0, 1); GRAM_OUT(2, 0, 2);
    GRAM_OUT(3, 0, 3); GRAM_OUT(4, 0, 4); GRAM_OUT(5, 0, 5); GRAM_OUT(6, 0, 6);
  } else if (w == 1) {
    GRAM_OUT(0, 1, 1); GRAM_OUT(1, 1, 2); GRAM_OUT(2, 1, 3);
    GRAM_OUT(3, 1, 4); GRAM_OUT(4, 1, 5); GRAM_OUT(5, 1, 6); GRAM_OUT(6, 2, 2);
  } else if (w == 2) {
    GRAM_OUT(0, 2, 3); GRAM_OUT(1, 2, 4); GRAM_OUT(2, 2, 5);
    GRAM_OUT(3, 2, 6); GRAM_OUT(4, 3, 3); GRAM_OUT(5, 3, 4); GRAM_OUT(6, 3, 5);
  } else {
    GRAM_OUT(0, 3, 6); GRAM_OUT(1, 4, 4); GRAM_OUT(2, 4, 5);
    GRAM_OUT(3, 4, 6); GRAM_OUT(4, 5, 5); GRAM_OUT(5, 5, 6); GRAM_OUT(6, 6, 6);
  }
}

// ------------------- K_fin2: GN2 params from Gram (parallelized) -----------
__global__ void k_fin2(const float* __restrict__ G, const float* __restrict__ w2,
                       const float* __restrict__ b2, const float* __restrict__ gm,
                       const float* __restrict__ bt, float* __restrict__ A2,
                       float* __restrict__ B2) {
  __shared__ float Gs[96][97];
  __shared__ float s1s[96], cs[96], cq[96];
  __shared__ float qp[96][4];
  __shared__ float gsum[8][2];
  const int b = blockIdx.x, t = threadIdx.x;   // 384 threads
  const int ch = t % 96, p = t / 96;
  for (int idx = t; idx < 9216; idx += 384) {
    int i = idx / 96, j = idx - i * 96;
    Gs[i][j] = ((i >> 4) <= (j >> 4)) ? G[b * 12544 + i * 112 + j]
                                      : G[b * 12544 + j * 112 + i];
  }
  if (t < 96) s1s[t] = G[b * 12544 + t * 112 + 96];
  __syncthreads();
  float wrow[96];
#pragma unroll
  for (int k = 0; k < 96; ++k) wrow[k] = w2[ch * 96 + k];
  float part = 0.f;
  for (int i = p * 24; i < p * 24 + 24; ++i) {
    float gi = 0.f;
#pragma unroll
    for (int jj = 0; jj < 96; ++jj) gi += Gs[i][jj] * wrow[jj];
    part += wrow[i] * gi;
  }
  qp[ch][p] = part;
  __syncthreads();
  if (t < 96) {
    float ds = 0.f;
#pragma unroll
    for (int k = 0; k < 96; ++k) ds += wrow[k] * s1s[k];
    float qf = qp[t][0] + qp[t][1] + qp[t][2] + qp[t][3];
    const float P = 131072.0f;
    cs[t] = ds + P * b2[t];
    cq[t] = qf + 2.0f * b2[t] * ds + P * b2[t] * b2[t];
  }
  __syncthreads();
  if (t < 8) {
    float s = 0.f, qq = 0.f;
    for (int k = 0; k < 12; ++k) { s += cs[t * 12 + k]; qq += cq[t * 12 + k]; }
    gsum[t][0] = s; gsum[t][1] = qq;
  }
  __syncthreads();
  if (t < 96) {
    int g = t / 12;
    float mean = gsum[g][0] * (1.0f / 1572864.0f);
    float var  = gsum[g][1] * (1.0f / 1572864.0f) - mean * mean;
    float r    = 1.0f / sqrtf(var + 1e-5f);
    float a    = gm[t] * r;
    A2[b * 96 + t] = a;
    B2[b * 96 + t] = bt[t] - mean * a;
  }
}

// ------------- K_main: conv1+conv2+conv3 (all MFMA) + pool + GN3 stats -----
// R20: (256,3) retry #4 — NOW audited to fit: bounce removal cut peak arch
// need to ~80 (a1[48]+temps in conv2; A3[48]+sg/qg[16] in conv3) <= 84 avail.
// LDS 53KB allows 3 blocks/CU. Tripwire: WRITE_SIZE must stay 12.5 MB.
__global__ __launch_bounds__(256, 3) void k_main(
    const unsigned short* __restrict__ fused, const float* __restrict__ b1,
    const float* __restrict__ st1g, const float* __restrict__ g1,
    const float* __restrict__ be1, const unsigned short* __restrict__ wh1,
    const unsigned short* __restrict__ wh2, const float* __restrict__ b2,
    const float* __restrict__ A2, const float* __restrict__ B2,
    const unsigned short* __restrict__ wh3, const float* __restrict__ b3,
    unsigned short* __restrict__ zmx, unsigned short* __restrict__ zmn,
    float* __restrict__ st) {
  __shared__ unsigned short shbuf[4 * 64 * 104];   // 53KB shared stage/tile
  __shared__ float b1s[96], A1s[96], B1s[96], b2s[96], A2s[96], B2s[96], b3s[192];
  __shared__ float pmx[4][192], pmn[4][192];
  __shared__ float red[16];

  const int t = threadIdx.x, lane = t & 63, w = t >> 6;
  const int l15 = lane & 15, q = lane >> 4;
  const int b = blockIdx.x >> 9;
  const int n0 = (blockIdx.x & 511) << 2;

  unsigned short (*x0bf)[40] = (unsigned short(*)[40])shbuf;          // [260][40]
  unsigned short (*x1w)[104] = (unsigned short(*)[104])(shbuf + w * 64 * 104);

  // ---- stage x0 (bf16) + params
  {
    size_t fb = (size_t)b * 10 * PPB + (size_t)n0 * 64;
    for (int idx = t; idx < 256 * 11; idx += 256) {   // zero cols 10..31
      int R = idx / 11, u = 5 + idx % 11;
      *(unsigned*)&x0bf[R][u * 2] = 0u;
    }
    for (int idx = t; idx < 2560; idx += 256) {       // fill cols 0..9
      int c = idx >> 8, R = idx & 255;
      x0bf[R][c] = fused[fb + (size_t)c * PPB + R];
    }
    if (t < 96) {
      b1s[t] = b1[t];
      b2s[t] = b2[t];  A2s[t] = A2[b * 96 + t];  B2s[t] = B2[b * 96 + t];
      int g = t / 12;   // fused fin1
      float s = st1g[b * 16 + 2 * g], qq = st1g[b * 16 + 2 * g + 1];
      float mean = s * (1.0f / 1572864.0f);
      float var  = qq * (1.0f / 1572864.0f) - mean * mean;
      float r    = 1.0f / sqrtf(var + 1e-5f);
      float a    = g1[t] * r;
      A1s[t] = a; B1s[t] = be1[t] - mean * a;
    }
    if (t < 192) b3s[t] = b3[t];
    if (t < 16) red[t] = 0.f;
  }
  __syncthreads();

  // ---- load x0 A-frags (all waves), then shbuf becomes per-wave x1 tile
  bf8_t af0[4];
#pragma unroll
  for (int rt = 0; rt < 4; ++rt)
    af0[rt] = *(const bf8_t*)&x0bf[w * 64 + rt * 16 + l15][q * 8];
  __syncthreads();   // all af0 in regs before overwrite

  // ---- conv1 via MFMA -> GN1+relu -> x1 tile (bf16, [pos][ch])
#pragma unroll
  for (int nt = 0; nt < 6; ++nt) {
    bf8_t bh = *(const bf8_t*)(wh1 + (((nt << 6) + lane) << 3));
    f4_t ac[4];
#pragma unroll
    for (int rt = 0; rt < 4; ++rt) {
      ac[rt] = (f4_t){0.f, 0.f, 0.f, 0.f};
      ac[rt] = __builtin_amdgcn_mfma_f32_16x16x32_bf16(af0[rt], bh, ac[rt], 0, 0, 0);
    }
    const int ch = nt * 16 + l15;
    const float A = A1s[ch], Bb = B1s[ch], bi = b1s[ch];
#pragma unroll
    for (int rt = 0; rt < 4; ++rt)
#pragma unroll
      for (int r = 0; r < 4; ++r) {
        float x = A * (ac[rt][r] + bi) + Bb;
        x1w[rt * 16 + q * 4 + r][ch] = f2bf(x > 0.f ? x : 0.f);
      }
  }
  __builtin_amdgcn_wave_barrier();
  bf8_t a1[4][3];
#pragma unroll
  for (int rt = 0; rt < 4; ++rt)
#pragma unroll
    for (int ks = 0; ks < 3; ++ks)
      a1[rt][ks] = *(const bf8_t*)&x1w[rt * 16 + l15][ks * 32 + q * 8];
  __builtin_amdgcn_wave_barrier();

  // ---- conv2 -> GN2+relu -> x2 tile (overwrite; a1 fully in regs)
#pragma unroll
  for (int nt = 0; nt < 6; ++nt) {
    f4_t ac[4];
#pragma unroll
    for (int rt = 0; rt < 4; ++rt) ac[rt] = (f4_t){0.f, 0.f, 0.f, 0.f};
#pragma unroll
    for (int ks = 0; ks < 3; ++ks) {
      bf8_t bh = *(const bf8_t*)(wh2 + ((((ks * 6 + nt) << 6) + lane) << 3));
#pragma unroll
      for (int rt = 0; rt < 4; ++rt)
        ac[rt] = __builtin_amdgcn_mfma_f32_16x16x32_bf16(a1[rt][ks], bh, ac[rt], 0, 0, 0);
    }
    const int ch = nt * 16 + l15;
    const float A = A2s[ch], Bb = B2s[ch], bi = b2s[ch];
#pragma unroll
    for (int rt = 0; rt < 4; ++rt)
#pragma unroll
      for (int r = 0; r < 4; ++r) {
        float x = A * (ac[rt][r] + bi) + Bb;
        x1w[rt * 16 + q * 4 + r][ch] = f2bf(x > 0.f ? x : 0.f);
      }
  }
  __builtin_amdgcn_wave_barrier();
  bf8_t A3[4][3];
#pragma unroll
  for (int rt = 0; rt < 4; ++rt)
#pragma unroll
    for (int ks = 0; ks < 3; ++ks)
      A3[rt][ks] = *(const bf8_t*)&x1w[rt * 16 + l15][ks * 32 + q * 8];
  __builtin_amdgcn_wave_barrier();

  // ---- conv3 per output tile + pool + GN3 stats
  float sg[8], qg[8];
#pragma unroll
  for (int g = 0; g < 8; ++g) { sg[g] = 0.f; qg[g] = 0.f; }
#pragma unroll
  for (int nt = 0; nt < 12; ++nt) {
    f4_t ac[4];
#pragma unroll
    for (int rt = 0; rt < 4; ++rt) ac[rt] = (f4_t){0.f, 0.f, 0.f, 0.f};
#pragma unroll
    for (int ks = 0; ks < 3; ++ks) {
      bf8_t bh = *(const bf8_t*)(wh3 + ((((ks * 12 + nt) << 6) + lane) << 3));
#pragma unroll
      for (int rt = 0; rt < 4; ++rt)
        ac[rt] = __builtin_amdgcn_mfma_f32_16x16x32_bf16(A3[rt][ks], bh, ac[rt], 0, 0, 0);
    }
    int ch = nt * 16 + l15;
    float bi = b3s[ch];
    float s = 0.f, qq = 0.f, mx = -3.4e38f, mn = 3.4e38f;
#pragma unroll
    for (int rt = 0; rt < 4; ++rt) {
#pragma unroll
      for (int r = 0; r < 4; ++r) {
        float v = ac[rt][r] + bi;
        s += v; qq += v * v;
        mx = fmaxf(mx, v); mn = fminf(mn, v);
      }
    }
    mx = fmaxf(mx, __shfl_xor(mx, 16)); mx = fmaxf(mx, __shfl_xor(mx, 32));
    mn = fminf(mn, __shfl_xor(mn, 16)); mn = fminf(mn, __shfl_xor(mn, 32));
    if (lane < 16) { pmx[w][nt * 16 + lane] = mx; pmn[w][nt * 16 + lane] = mn; }
    const int g0 = (nt * 16) / 24;
    const int g1i = (nt * 16 + 15) / 24;
    if (g0 == g1i) {
      sg[g0] += s; qg[g0] += qq;
    } else {
      const int cut = g1i * 24 - nt * 16;
      if (l15 < cut) { sg[g0] += s; qg[g0] += qq; }
      else           { sg[g1i] += s; qg[g1i] += qq; }
    }
  }

#pragma unroll
  for (int g = 0; g < 8; ++g) {
#pragma unroll
    for (int off = 1; off < 64; off <<= 1) {
      sg[g] += __shfl_xor(sg[g], off);
      qg[g] += __shfl_xor(qg[g], off);
    }
  }
  if (lane == 0) {
#pragma unroll
    for (int g = 0; g < 8; ++g) {
      atomicAdd(&red[2 * g + 0], sg[g]);
      atomicAdd(&red[2 * g + 1], qg[g]);
    }
  }
  {
    int n = n0 + w;
    size_t ob = ((size_t)(b * NPTS + n)) * 192;
    for (int i = lane; i < 192; i += 64) {
      zmx[ob + i] = f2bf(pmx[w][i]);
      zmn[ob + i] = f2bf(pmn[w][i]);
    }
  }
  __syncthreads();
  if (t < 16) atomicAdd(&st[b * 16 + t], red[t]);
}

// ---------- K_post1 (MFMA): GN3+relu -> conv4 -> z4bf + GN4 stats ----------
__global__ __launch_bounds__(128) void k_post1(
    const unsigned short* __restrict__ zmx, const unsigned short* __restrict__ zmn,
    const float* __restrict__ st3, const float* __restrict__ g3,
    const float* __restrict__ be3, const unsigned short* __restrict__ wh4,
    const float* __restrict__ b4, unsigned short* __restrict__ z4bf,
    float* __restrict__ st4) {
  __shared__ unsigned short ybf[32][200];   // bf16 activations; reused as zbuf
  __shared__ float A3s[192], B3s[192], b4s[192];
  __shared__ float red[16];
  const int t = threadIdx.x, lane = t & 63, w = t >> 6;
  const int l15 = lane & 15, q = lane >> 4;
  const int p0 = blockIdx.x << 5;
  const int b = p0 >> 11;

  for (int c = t; c < 192; c += 128) {   // fused fin3
    int g = c / 24;
    float s = st3[b * 16 + 2 * g], qq = st3[b * 16 + 2 * g + 1];
    float mean = s * (1.0f / 3145728.0f);
    float var  = qq * (1.0f / 3145728.0f) - mean * mean;
    float r    = 1.0f / sqrtf(var + 1e-5f);
    float a    = g3[c] * r;
    A3s[c] = a; B3s[c] = be3[c] - mean * a; b4s[c] = b4[c];
  }
  if (t < 16) red[t] = 0.f;
  __syncthreads();

  for (int idx = t; idx < 32 * 192; idx += 128) {
    int ptl = idx / 192, ch = idx - ptl * 192;
    float A = A3s[ch];
    const unsigned short* src = (A > 0.f) ? zmx : zmn;
    float x = A * bf2f(src[(size_t)(p0 + ptl) * 192 + ch]) + B3s[ch];
    ybf[ptl][ch] = f2bf(x > 0.f ? x : 0.f);
  }
  __syncthreads();

  bf8_t af[6];
#pragma unroll
  for (int ks = 0; ks < 6; ++ks)
    af[ks] = *(const bf8_t*)&ybf[w * 16 + l15][ks * 32 + q * 8];
  __syncthreads();   // ybf free -> becomes zbuf

  float sg[8], qg[8];
#pragma unroll
  for (int g = 0; g < 8; ++g) { sg[g] = 0.f; qg[g] = 0.f; }
#pragma unroll
  for (int nt = 0; nt < 12; ++nt) {
    f4_t ac = (f4_t){0.f, 0.f, 0.f, 0.f};
#pragma unroll
    for (int ks = 0; ks < 6; ++ks) {
      bf8_t bh = *(const bf8_t*)(wh4 + ((((ks * 12 + nt) << 6) + lane) << 3));
      ac = __builtin_amdgcn_mfma_f32_16x16x32_bf16(af[ks], bh, ac, 0, 0, 0);
    }
    int ch = nt * 16 + l15;
    float bi = b4s[ch];
    float s = 0.f, qq = 0.f;
#pragma unroll
    for (int r = 0; r < 4; ++r) {
      float v = ac[r] + bi;
      s += v; qq += v * v;
      ybf[w * 16 + q * 4 + r][ch] = f2bf(v);   // zbuf (wave-private rows)
    }
    const int g0 = (nt * 16) / 24;
    const int g1i = (nt * 16 + 15) / 24;
    if (g0 == g1i) {
      sg[g0] += s; qg[g0] += qq;
    } else {
      const int cut = g1i * 24 - nt * 16;
      if (l15 < cut) { sg[g0] += s; qg[g0] += qq; }
      else           { sg[g1i] += s; qg[g1i] += qq; }
    }
  }
#pragma unroll
  for (int g = 0; g < 8; ++g) {
#pragma unroll
    for (int off = 1; off < 64; off <<= 1) {
      sg[g] += __shfl_xor(sg[g], off);
      qg[g] += __shfl_xor(qg[g], off);
    }
  }
  if (lane == 0) {
#pragma unroll
    for (int g = 0; g < 8; ++g) {
      atomicAdd(&red[2 * g + 0], sg[g]);
      atomicAdd(&red[2 * g + 1], qg[g]);
    }
  }
  __syncthreads();
  unsigned* z4u = (unsigned*)z4bf;
  for (int idx = t; idx < 32 * 96; idx += 128) {
    int ptl = idx / 96, pr = idx - ptl * 96;
    z4u[(size_t)(p0 + ptl) * 96 + pr] = *(const unsigned*)&ybf[ptl][pr * 2];
  }
  if (t < 16) atomicAdd(&st4[b * 16 + t], red[t]);
}

// ---------- K_post2 (MFMA): GN4+relu -> conv5 -> z5bf + GN5 stats ----------
__global__ __launch_bounds__(128) void k_post2(
    const unsigned short* __restrict__ z4bf, const float* __restrict__ st4,
    const float* __restrict__ g4, const float* __restrict__ be4,
    const unsigned short* __restrict__ wh5, const float* __restrict__ b5,
    unsigned short* __restrict__ z5bf, float* __restrict__ st5) {
  __shared__ unsigned short ybf[32][200];
  __shared__ float A4s[192], B4s[192], b5s[96];
  __shared__ float red[16];
  const int t = threadIdx.x, lane = t & 63, w = t >> 6;
  const int l15 = lane & 15, q = lane >> 4;
  const int p0 = blockIdx.x << 5;
  const int b = p0 >> 11;

  for (int c = t; c < 192; c += 128) {   // fused fin4 (count = 2048*24)
    int g = c / 24;
    float s = st4[b * 16 + 2 * g], qq = st4[b * 16 + 2 * g + 1];
    float mean = s * (1.0f / 49152.0f);
    float var  = qq * (1.0f / 49152.0f) - mean * mean;
    float r    = 1.0f / sqrtf(var + 1e-5f);
    float a    = g4[c] * r;
    A4s[c] = a; B4s[c] = be4[c] - mean * a;
  }
  if (t < 96) b5s[t] = b5[t];
  if (t < 16) red[t] = 0.f;
  __syncthreads();

  const unsigned* z4u = (const unsigned*)z4bf;
  for (int idx = t; idx < 32 * 96; idx += 128) {
    int ptl = idx / 96, pr = idx - ptl * 96;
    unsigned v = z4u[(size_t)(p0 + ptl) * 96 + pr];
    int ch = pr * 2;
    float x0 = A4s[ch] * bf2f((unsigned short)(v & 0xffff)) + B4s[ch];
    float x1 = A4s[ch + 1] * bf2f((unsigned short)(v >> 16)) + B4s[ch + 1];
    x0 = x0 > 0.f ? x0 : 0.f;
    x1 = x1 > 0.f ? x1 : 0.f;
    *(unsigned*)&ybf[ptl][ch] = cvt_pk_bf16(x0, x1);
  }
  __syncthreads();

  bf8_t af[6];
#pragma unroll
  for (int ks = 0; ks < 6; ++ks)
    af[ks] = *(const bf8_t*)&ybf[w * 16 + l15][ks * 32 + q * 8];
  __syncthreads();

  float sg[8], qg[8];
#pragma unroll
  for (int g = 0; g < 8; ++g) { sg[g] = 0.f; qg[g] = 0.f; }
#pragma unroll
  for (int nt = 0; nt < 6; ++nt) {
    f4_t ac = (f4_t){0.f, 0.f, 0.f, 0.f};
#pragma unroll
    for (int ks = 0; ks < 6; ++ks) {
      bf8_t bh = *(const bf8_t*)(wh5 + ((((ks * 6 + nt) << 6) + lane) << 3));
      ac = __builtin_amdgcn_mfma_f32_16x16x32_bf16(af[ks], bh, ac, 0, 0, 0);
    }
    int ch = nt * 16 + l15;
    float bi = b5s[ch];
    float s = 0.f, qq = 0.f;
#pragma unroll
    for (int r = 0; r < 4; ++r) {
      float v = ac[r] + bi;
      s += v; qq += v * v;
      ybf[w * 16 + q * 4 + r][ch] = f2bf(v);
    }
    const int g0 = (nt * 16) / 12;
    const int g1i = (nt * 16 + 15) / 12;
    const int cut = g1i * 12 - nt * 16;
    if (l15 < cut) { sg[g0] += s; qg[g0] += qq; }
    else           { sg[g1i] += s; qg[g1i] += qq; }
  }
#pragma unroll
  for (int g = 0; g < 8; ++g) {
#pragma unroll
    for (int off = 1; off < 64; off <<= 1) {
      sg[g] += __shfl_xor(sg[g], off);
      qg[g] += __shfl_xor(qg[g], off);
    }
  }
  if (lane == 0) {
#pragma unroll
    for (int g = 0; g < 8; ++g) {
      atomicAdd(&red[2 * g + 0], sg[g]);
      atomicAdd(&red[2 * g + 1], qg[g]);
    }
  }
  __syncthreads();
  unsigned* z5u = (unsigned*)z5bf;
  for (int idx = t; idx < 32 * 48; idx += 128) {
    int ptl = idx / 48, pr = idx - ptl * 48;
    z5u[(size_t)(p0 + ptl) * 48 + pr] = *(const unsigned*)&ybf[ptl][pr * 2];
  }
  if (t < 16) atomicAdd(&st5[b * 16 + t], red[t]);
}

// ------- K_post3 (f32, LDS weights): GN5+relu -> conv6 -> L2-norm -> out ---
__global__ __launch_bounds__(128) void k_post3(
    const unsigned short* __restrict__ z5bf, const float* __restrict__ st5,
    const float* __restrict__ g5, const float* __restrict__ be5,
    const float* __restrict__ w6, const float* __restrict__ b6,
    float* __restrict__ out) {
  __shared__ float y[32][100];        // f32 activations; reused as zs
  __shared__ float w6s[96][96];
  __shared__ float A5s[96], B5s[96], b6s[96];
  __shared__ float inv[32];
  const int t = threadIdx.x;
  const int ptl = t & 31, grp = t >> 5;
  const int p0 = blockIdx.x << 5;
  const int b = p0 >> 11;

  if (t < 96) {   // fused fin5 (count = 2048*12)
    int g = t / 12;
    float s = st5[b * 16 + 2 * g], qq = st5[b * 16 + 2 * g + 1];
    float mean = s * (1.0f / 24576.0f);
    float var  = qq * (1.0f / 24576.0f) - mean * mean;
    float r    = 1.0f / sqrtf(var + 1e-5f);
    float a    = g5[t] * r;
    A5s[t] = a; B5s[t] = be5[t] - mean * a; b6s[t] = b6[t];
  }
  for (int idx = t; idx < 9216; idx += 128)
    w6s[idx / 96][idx % 96] = w6[idx];
  __syncthreads();

  const unsigned* z5u = (const unsigned*)z5bf;
  for (int idx = t; idx < 32 * 48; idx += 128) {
    int pl = idx / 48, pr = idx - pl * 48;
    unsigned v = z5u[(size_t)(p0 + pl) * 48 + pr];
    int ch = pr * 2;
    float x0 = A5s[ch] * bf2f((unsigned short)(v & 0xffff)) + B5s[ch];
    float x1 = A5s[ch + 1] * bf2f((unsigned short)(v >> 16)) + B5s[ch + 1];
    y[pl][ch]     = x0 > 0.f ? x0 : 0.f;
    y[pl][ch + 1] = x1 > 0.f ? x1 : 0.f;
  }
  __syncthreads();

  const int ob = grp * 24;
  float z[24];
#pragma unroll
  for (int kb = 0; kb < 3; ++kb) {
    float a[8];
#pragma unroll
    for (int k = 0; k < 8; ++k) a[k] = b6s[ob + kb * 8 + k];
    for (int c4 = 0; c4 < 24; ++c4) {
      float4 xv = *(const float4*)&y[ptl][c4 * 4];
#pragma unroll
      for (int k = 0; k < 8; ++k) {
        const float* wr = &w6s[ob + kb * 8 + k][c4 * 4];
        a[k] += wr[0] * xv.x + wr[1] * xv.y + wr[2] * xv.z + wr[3] * xv.w;
      }
    }
#pragma unroll
    for (int k = 0; k < 8; ++k) z[kb * 8 + k] = a[k];
  }
  __syncthreads();   // all reads of y done -> reuse as zs
#pragma unroll
  for (int jj = 0; jj < 24; ++jj) y[ptl][ob + jj] = z[jj];
  __syncthreads();
  if (t < 32) {
    float ss = 0.f;
#pragma unroll
    for (int c = 0; c < 96; ++c) { float v = y[t][c]; ss += v * v; }
    float nf = (ss < 1e-20f) ? 0.0f : sqrtf(ss);
    inv[t] = 1.0f / nf;
  }
  __syncthreads();
  for (int idx = t; idx < 32 * 96; idx += 128) {
    int pl = idx / 96, ch = idx - pl * 96;
    out[(size_t)(p0 + pl) * 96 + ch] = y[pl][ch] * inv[pl];
  }
}

// --------------------------------------------------------------- launch ----
extern "C" void kernel_launch(void* const* d_in, const int* in_sizes, int n_in,
                              void* d_out, int out_size, void* d_ws, size_t ws_size,
                              hipStream_t stream) {
  (void)in_sizes; (void)n_in; (void)out_size; (void)ws_size;
  const float* xyz = (const float*)d_in[0];
  const float* nrm = (const float*)d_in[1];
  const float* w1 = (const float*)d_in[2];  const float* b1 = (const float*)d_in[3];
  const float* g1 = (const float*)d_in[4];  const float* be1 = (const float*)d_in[5];
  const float* w2 = (const float*)d_in[6];  const float* b2 = (const float*)d_in[7];
  const float* g2 = (const float*)d_in[8];  const float* be2 = (const float*)d_in[9];
  const float* w3 = (const float*)d_in[10]; const float* b3 = (const float*)d_in[11];
  const float* g3 = (const float*)d_in[12]; const float* be3 = (const float*)d_in[13];
  const float* w4 = (const float*)d_in[14]; const float* b4 = (const float*)d_in[15];
  const float* g4 = (const float*)d_in[16]; const float* be4 = (const float*)d_in[17];
  const float* w5 = (const float*)d_in[18]; const float* b5 = (const float*)d_in[19];
  const float* g5 = (const float*)d_in[20]; const float* be5 = (const float*)d_in[21];
  const float* w6 = (const float*)d_in[22]; const float* b6 = (const float*)d_in[23];

  float* ws = (float*)d_ws;
  unsigned short* fused = (unsigned short*)ws;   // 10,485,760 ushorts = 5,242,880 f
  unsigned short* zmxbf = (unsigned short*)(ws + 5242880);   // 3,145,728 ushorts
  unsigned short* zmnbf = zmxbf + 3145728;                   // 3,145,728 ushorts
  float* st1 = ws + 5242880 + 3145728;  //  128 each (after 2x1,572,864 f)
  float* st3 = st1 + 128;
  float* st4 = st3 + 128;
  float* st5 = st4 + 128;
  float* A2 = st5 + 128;  float* B2 = A2 + 768;
  float* wbuf = B2 + 768;               // bf16 frags: 86,016 ushorts = 43,008 f
  unsigned short* wh1 = (unsigned short*)wbuf;   //  3072
  unsigned short* wh2 = wh1 + 3072;              //  9216
  unsigned short* wh3 = wh2 + 9216;              // 18432
  unsigned short* wh4 = wh3 + 18432;             // 36864
  unsigned short* wh5 = wh4 + 36864;             // 18432
  float* G = wbuf + 43008;              // 8 x 12544 floats
  unsigned short* z4bf = (unsigned short*)(G + 100352);   // 3,145,728 ushorts
  unsigned short* z5bf = z4bf + 3145728;                  // 1,572,864 ushorts

  hipMemsetAsync(st1, 0, 4 * 128 * sizeof(float), stream);
  hipMemsetAsync(G, 0, 8 * 12544 * sizeof(float), stream);

  k_wprep <<<336, 256, 0, stream>>>(w1, w2, w3, w4, w5, wh1, wh2, wh3, wh4, wh5);
  k_feat  <<<4096, 256, 0, stream>>>(xyz, nrm, w1, b1, fused, st1);
  k_gram  <<<512, 256, 0, stream>>>(fused, wh1, b1, st1, g1, be1, G);
  k_fin2  <<<8, 384, 0, stream>>>(G, w2, b2, g2, be2, A2, B2);
  k_main  <<<4096, 256, 0, stream>>>(fused, b1, st1, g1, be1, wh1, wh2, b2, A2, B2,
                                     wh3, b3, zmxbf, zmnbf, st3);
  k_post1 <<<512, 128, 0, stream>>>(zmxbf, zmnbf, st3, g3, be3, wh4, b4, z4bf, st4);
  k_post2 <<<512, 128, 0, stream>>>(z4bf, st4, g4, be4, wh5, b5, z5bf, st5);
  k_post3 <<<512, 128, 0, stream>>>(z5bf, st5, g5, be5, w6, b6, (float*)d_out);
}

// Round 21
// 436.935 us; speedup vs baseline: 1.2522x; 1.2522x over previous
//
#include <hip/hip_runtime.h>
#include <math.h>

#define NPTS 2048
#define PPB  131072   // positions per batch = 2048 * 64

typedef __attribute__((ext_vector_type(8))) short bf8_t;   // 8 bf16 (4 VGPRs)
typedef __attribute__((ext_vector_type(4))) float f4_t;    // MFMA accumulator

__device__ __forceinline__ unsigned short f2bf(float x) {
  unsigned u = __float_as_uint(x);
  u += 0x7FFFu + ((u >> 16) & 1u);          // RNE
  return (unsigned short)(u >> 16);
}
__device__ __forceinline__ float bf2f(unsigned short h) {
  return __uint_as_float(((unsigned)h) << 16);
}
// 2 f32 -> packed 2xbf16 in one VALU op (low half = a, high half = b; RNE)
__device__ __forceinline__ unsigned cvt_pk_bf16(float a, float b) {
  unsigned r;
  asm("v_cvt_pk_bf16_f32 %0, %1, %2" : "=v"(r) : "v"(a), "v"(b));
  return r;
}

// ---------------------------------------------------------------- angle ----
__device__ __forceinline__ float angle_f(float ax, float ay, float az,
                                         float bx, float by, float bz) {
  float cx = ay * bz - az * by;
  float cy = az * bx - ax * bz;
  float cz = ax * by - ay * bx;
  float cn = cx * cx + cy * cy + cz * cz;
  float dt = ax * bx + ay * by + az * bz;
  bool  sml = cn < 1e-20f;
  bool  deg = sml && (fabsf(dt) < 1e-12f);
  float cns = sml ? 0.0f : sqrtf(cn);
  float ang = atan2f(cns, dt);
  return deg ? 0.0f : ang;
}

// --------------- weight prep: bf16 frags for conv1/2/3 and post1/2 --------
__global__ __launch_bounds__(256) void k_wprep(
    const float* __restrict__ w1, const float* __restrict__ w2,
    const float* __restrict__ w3, const float* __restrict__ w4,
    const float* __restrict__ w5,
    unsigned short* __restrict__ wh1, unsigned short* __restrict__ wh2,
    unsigned short* __restrict__ wh3, unsigned short* __restrict__ wh4,
    unsigned short* __restrict__ wh5) {
  int t = blockIdx.x * 256 + threadIdx.x;
  if (t < 3072) {            // conv1: 1 ks * 6 nt (96x10, K padded to 32)
    int i = t & 7, lane = (t >> 3) & 63, nt = t >> 9;
    int k = ((lane >> 4) << 3) + i;
    int n = nt * 16 + (lane & 15);
    wh1[t] = (k < 10) ? f2bf(w1[n * 10 + k]) : (unsigned short)0;
  } else if (t < 12288) {    // conv2: 3 ks * 6 nt (96x96)
    int f = t - 3072;
    int i = f & 7, lane = (f >> 3) & 63, r = f >> 9, nt = r % 6, ks = r / 6;
    int k = ks * 32 + ((lane >> 4) << 3) + i;
    int n = nt * 16 + (lane & 15);
    wh2[f] = f2bf(w2[n * 96 + k]);
  } else if (t < 30720) {    // conv3: 3 ks * 12 nt (192x96)
    int f = t - 12288;
    int i = f & 7, lane = (f >> 3) & 63, r = f >> 9, nt = r % 12, ks = r / 12;
    int k = ks * 32 + ((lane >> 4) << 3) + i;
    int n = nt * 16 + (lane & 15);
    wh3[f] = f2bf(w3[n * 96 + k]);
  } else if (t < 67584) {    // post1: 6 ks * 12 nt (192x192)
    int f = t - 30720;
    int i = f & 7, lane = (f >> 3) & 63, r = f >> 9, nt = r % 12, ks = r / 12;
    int k = ks * 32 + ((lane >> 4) << 3) + i;
    int n = nt * 16 + (lane & 15);
    wh4[f] = f2bf(w4[n * 192 + k]);
  } else if (t < 86016) {    // post2: 6 ks * 6 nt (96x192)
    int f = t - 67584;
    int i = f & 7, lane = (f >> 3) & 63, r = f >> 9, nt = r % 6, ks = r / 6;
    int k = ks * 32 + ((lane >> 4) << 3) + i;
    int n = nt * 16 + (lane & 15);
    wh5[f] = f2bf(w5[n * 192 + k]);
  }
}

// ---------------------------------------------------- K1: neighbors+feat ----
__global__ __launch_bounds__(256) void k_feat(
    const float* __restrict__ xyz, const float* __restrict__ nrm,
    const float* __restrict__ w1, const float* __restrict__ b1,
    unsigned short* __restrict__ fused, float* __restrict__ st) {
  const int wid = threadIdx.x >> 6, lane = threadIdx.x & 63;
  const int b = blockIdx.x >> 9;
  const int n = ((blockIdx.x & 511) << 2) + wid;
  const float* X  = xyz + (size_t)b * NPTS * 3;
  const float* NR = nrm + (size_t)b * NPTS * 3;
  __shared__ int   lst[4][64];
  __shared__ float red[16];

  const float xi0 = X[n * 3 + 0], xi1 = X[n * 3 + 1], xi2 = X[n * 3 + 2];

  int cnt = 0;
  for (int jb = 0; jb < NPTS; jb += 64) {
    int   j  = jb + lane;
    float dx = __fsub_rn(xi0, X[j * 3 + 0]);
    float dy = __fsub_rn(xi1, X[j * 3 + 1]);
    float dz = __fsub_rn(xi2, X[j * 3 + 2]);
    float sq = __fadd_rn(__fadd_rn(__fmul_rn(dx, dx), __fmul_rn(dy, dy)),
                         __fmul_rn(dz, dz));
    bool act = (sq <= 0.09f);
    unsigned long long m = __ballot(act);
    int pos = cnt + __popcll(m & ((1ull << lane) - 1ull));
    if (act && pos < 64) lst[wid][pos] = j;
    cnt += __popcll(m);
    if (cnt >= 64) break;
  }
  __syncthreads();

  const int j = lst[wid][(lane < cnt) ? lane : 0];

  const float gx = X[j * 3 + 0],  gy = X[j * 3 + 1],  gz = X[j * 3 + 2];
  const float gnx = NR[j * 3 + 0], gny = NR[j * 3 + 1], gnz = NR[j * 3 + 2];
  const float nix = NR[n * 3 + 0], niy = NR[n * 3 + 1], niz = NR[n * 3 + 2];
  const float dx = gx - xi0, dy = gy - xi1, dz = gz - xi2;

  float f[10];
  f[0] = xi0; f[1] = xi1; f[2] = xi2;
  f[3] = dx;  f[4] = dy;  f[5] = dz;
  f[6] = angle_f(nix, niy, niz, dx, dy, dz);
  f[7] = angle_f(gnx, gny, gnz, dx, dy, dz);
  f[8] = angle_f(nix, niy, niz, gnx, gny, gnz);
  float ss = dx * dx + dy * dy + dz * dz;
  f[9] = (ss < 1e-20f) ? 0.0f : sqrtf(ss);

  size_t base = (size_t)b * 10 * PPB + (size_t)n * 64 + lane;
#pragma unroll
  for (int c = 0; c < 10; ++c) fused[base + (size_t)c * PPB] = f2bf(f[c]);

  float sg[8], qg[8];
#pragma unroll
  for (int g = 0; g < 8; ++g) {
    float s = 0.f, q = 0.f;
#pragma unroll
    for (int t2 = 0; t2 < 12; ++t2) {
      const int o = g * 12 + t2;
      float a = b1[o];
#pragma unroll
      for (int c = 0; c < 10; ++c) a += w1[o * 10 + c] * f[c];
      s += a; q += a * a;
    }
    sg[g] = s; qg[g] = q;
  }
#pragma unroll
  for (int g = 0; g < 8; ++g) {
#pragma unroll
    for (int off = 32; off; off >>= 1) {
      sg[g] += __shfl_xor(sg[g], off);
      qg[g] += __shfl_xor(qg[g], off);
    }
  }
  if (threadIdx.x < 16) red[threadIdx.x] = 0.f;
  __syncthreads();
  if (lane == 0) {
#pragma unroll
    for (int g = 0; g < 8; ++g) {
      atomicAdd(&red[2 * g + 0], sg[g]);
      atomicAdd(&red[2 * g + 1], qg[g]);
    }
  }
  __syncthreads();
  if (threadIdx.x < 16) atomicAdd(&st[b * 16 + threadIdx.x], red[threadIdx.x]);
}

// ---------------------- K_gram: conv1 (MFMA) -> x1, G = sum x1~ x1~^T ------
#define GRAM_TILE(i, MT, NT) \
  acc[i] = __builtin_amdgcn_mfma_f32_16x16x32_bf16(fh##MT, fh##NT, acc[i], 0, 0, 0);
#define GRAM_LD(T) \
  bf8_t fh##T = *(const bf8_t*)&x1h[pp][T * 16 + l15][ko];
#define GRAM_OUT(i, MT, NT) do { \
  _Pragma("unroll") \
  for (int r = 0; r < 4; ++r) \
    atomicAdd(&Gb[(MT * 16 + q * 4 + r) * 112 + NT * 16 + l15], acc[i][r]); \
} while (0)

__global__ __launch_bounds__(256) void k_gram(
    const unsigned short* __restrict__ fused, const unsigned short* __restrict__ wh1,
    const float* __restrict__ b1, const float* __restrict__ st1g,
    const float* __restrict__ g1, const float* __restrict__ be1,
    float* __restrict__ G) {
  __shared__ unsigned short x1h[2][112][72];
  __shared__ unsigned short x0bf[128][40];   // bf16 x0, K-padded (2 points)
  __shared__ float A1s[96], B1s[96], b1s[96];
  const int t = threadIdx.x, lane = t & 63, w = t >> 6;
  const int l15 = lane & 15, q = lane >> 4;
  const int b = blockIdx.x >> 6;          // 512 blocks = 8 batches x 64
  const int blk = blockIdx.x & 63;        // 32 points each (16 iters x 2)

  if (t < 96) {   // fused fin1
    int g = t / 12;
    float s = st1g[b * 16 + 2 * g], qq = st1g[b * 16 + 2 * g + 1];
    float mean = s * (1.0f / 1572864.0f);
    float var  = qq * (1.0f / 1572864.0f) - mean * mean;
    float r    = 1.0f / sqrtf(var + 1e-5f);
    float a    = g1[t] * r;
    A1s[t] = a; B1s[t] = be1[t] - mean * a; b1s[t] = b1[t];
  }
  for (int idx = t; idx < 2 * 16 * 72; idx += 256) {  // ones row 96, zeros 97..111
    int pp = idx / (16 * 72), rem = idx % (16 * 72);
    int ch = 96 + rem / 72, rr = rem % 72;
    x1h[pp][ch][rr] = (ch == 96) ? (unsigned short)0x3F80 : (unsigned short)0;
  }
  __syncthreads();

  f4_t acc[7];
#pragma unroll
  for (int i = 0; i < 7; ++i) acc[i] = (f4_t){0.f, 0.f, 0.f, 0.f};

  for (int it = 0; it < 16; ++it) {
    int n = blk * 32 + it * 2;
    size_t fb = (size_t)b * 10 * PPB + (size_t)n * 64;
    __syncthreads();   // prior Gram reads done before overwrite
    for (int idx = t; idx < 128 * 11; idx += 256) {  // zero cols 10..31
      int R = idx / 11, u = 5 + idx % 11;
      *(unsigned*)&x0bf[R][u * 2] = 0u;
    }
    for (int idx = t; idx < 1280; idx += 256) {      // fill cols 0..9 (2 pts)
      int c = idx >> 7, s = idx & 127;
      x0bf[s][c] = fused[fb + (size_t)c * PPB + s];
    }
    __syncthreads();
    // conv1 via MFMA for both points: wave w owns rows w*16..w*16+15 of each
#pragma unroll
    for (int pp = 0; pp < 2; ++pp) {
      bf8_t af0 = *(const bf8_t*)&x0bf[pp * 64 + w * 16 + l15][q * 8];
#pragma unroll
      for (int nt = 0; nt < 6; ++nt) {
        f4_t a1c = (f4_t){0.f, 0.f, 0.f, 0.f};
        bf8_t bh = *(const bf8_t*)(wh1 + (((nt << 6) + lane) << 3));
        a1c = __builtin_amdgcn_mfma_f32_16x16x32_bf16(af0, bh, a1c, 0, 0, 0);
        const int ch = nt * 16 + l15;
        const float A = A1s[ch], Bb = B1s[ch], bi = b1s[ch];
#pragma unroll
        for (int r = 0; r < 4; ++r) {
          float x = A * (a1c[r] + bi) + Bb;
          x1h[pp][ch][w * 16 + q * 4 + r] = f2bf(x > 0.f ? x : 0.f);
        }
      }
    }
    __syncthreads();
#pragma unroll
    for (int pp = 0; pp < 2; ++pp) {
#pragma unroll
      for (int ksr = 0; ksr < 2; ++ksr) {
        const int ko = ksr * 32 + q * 8;
        GRAM_LD(0) GRAM_LD(1) GRAM_LD(2) GRAM_LD(3) GRAM_LD(4) GRAM_LD(5) GRAM_LD(6)
        if (w == 0) {
          GRAM_TILE(0, 0, 0); GRAM_TILE(1, 0, 1); GRAM_TILE(2, 0, 2);
          GRAM_TILE(3, 0, 3); GRAM_TILE(4, 0, 4); GRAM_TILE(5, 0, 5); GRAM_TILE(6, 0, 6);
        } else if (w == 1) {
          GRAM_TILE(0, 1, 1); GRAM_TILE(1, 1, 2); GRAM_TILE(2, 1, 3);
          GRAM_TILE(3, 1, 4); GRAM_TILE(4, 1, 5); GRAM_TILE(5, 1, 6); GRAM_TILE(6, 2, 2);
        } else if (w == 2) {
          GRAM_TILE(0, 2, 3); GRAM_TILE(1, 2, 4); GRAM_TILE(2, 2, 5);
          GRAM_TILE(3, 2, 6); GRAM_TILE(4, 3, 3); GRAM_TILE(5, 3, 4); GRAM_TILE(6, 3, 5);
        } else {
          GRAM_TILE(0, 3, 6); GRAM_TILE(1, 4, 4); GRAM_TILE(2, 4, 5);
          GRAM_TILE(3, 4, 6); GRAM_TILE(4, 5, 5); GRAM_TILE(5, 5, 6); GRAM_TILE(6, 6, 6);
        }
      }
    }
  }
  float* Gb = G + (size_t)b * 12544;
  if (w == 0) {
    GRAM_OUT(0, 0, 0); GRAM_OUT(1, 0, 1); GRAM_OUT(2, 0, 2);
    GRAM_OUT(3, 0, 3); GRAM_OUT(4, 0, 4); GRAM_OUT(5, 0, 5); GRAM_OUT(6, 0, 6);
  } else if (w == 1) {
    GRAM_OUT(0, 1, 1); GRAM_OUT(1, 1, 2); GRAM_OUT(2, 1, 3);
    GRAM_OUT(3, 1, 4); GRAM_OUT(4, 1, 5); GRAM_OUT(5, 1, 6); GRAM_OUT(6, 2, 2);
  } else if (w == 2) {
    GRAM_OUT(0, 2, 3); GRAM_OUT(1, 2, 4); GRAM_OUT(2, 2, 5);
    GRAM_OUT(3, 2, 6); GRAM_OUT(4, 3, 3); GRAM_OUT(5, 3, 4); GRAM_OUT(6, 3, 5);
  } else {
    GRAM_OUT(0, 3, 6); GRAM_OUT(1, 4, 4); GRAM_OUT(2, 4, 5);
    GRAM_OUT(3, 4, 6); GRAM_OUT(4, 5, 5); GRAM_OUT(5, 5, 6); GRAM_OUT(6, 6, 6);
  }
}

// ------------------- K_fin2: GN2 params from Gram (parallelized) -----------
__global__ void k_fin2(const float* __restrict__ G, const float* __restrict__ w2,
                       const float* __restrict__ b2, const float* __restrict__ gm,
                       const float* __restrict__ bt, float* __restrict__ A2,
                       float* __restrict__ B2) {
  __shared__ float Gs[96][97];
  __shared__ float s1s[96], cs[96], cq[96];
  __shared__ float qp[96][4];
  __shared__ float gsum[8][2];
  const int b = blockIdx.x, t = threadIdx.x;   // 384 threads
  const int ch = t % 96, p = t / 96;
  for (int idx = t; idx < 9216; idx += 384) {
    int i = idx / 96, j = idx - i * 96;
    Gs[i][j] = ((i >> 4) <= (j >> 4)) ? G[b * 12544 + i * 112 + j]
                                      : G[b * 12544 + j * 112 + i];
  }
  if (t < 96) s1s[t] = G[b * 12544 + t * 112 + 96];
  __syncthreads();
  float wrow[96];
#pragma unroll
  for (int k = 0; k < 96; ++k) wrow[k] = w2[ch * 96 + k];
  float part = 0.f;
  for (int i = p * 24; i < p * 24 + 24; ++i) {
    float gi = 0.f;
#pragma unroll
    for (int jj = 0; jj < 96; ++jj) gi += Gs[i][jj] * wrow[jj];
    part += wrow[i] * gi;
  }
  qp[ch][p] = part;
  __syncthreads();
  if (t < 96) {
    float ds = 0.f;
#pragma unroll
    for (int k = 0; k < 96; ++k) ds += wrow[k] * s1s[k];
    float qf = qp[t][0] + qp[t][1] + qp[t][2] + qp[t][3];
    const float P = 131072.0f;
    cs[t] = ds + P * b2[t];
    cq[t] = qf + 2.0f * b2[t] * ds + P * b2[t] * b2[t];
  }
  __syncthreads();
  if (t < 8) {
    float s = 0.f, qq = 0.f;
    for (int k = 0; k < 12; ++k) { s += cs[t * 12 + k]; qq += cq[t * 12 + k]; }
    gsum[t][0] = s; gsum[t][1] = qq;
  }
  __syncthreads();
  if (t < 96) {
    int g = t / 12;
    float mean = gsum[g][0] * (1.0f / 1572864.0f);
    float var  = gsum[g][1] * (1.0f / 1572864.0f) - mean * mean;
    float r    = 1.0f / sqrtf(var + 1e-5f);
    float a    = gm[t] * r;
    A2[b * 96 + t] = a;
    B2[b * 96 + t] = bt[t] - mean * a;
  }
}

// ------------- K_main: conv1+conv2+conv3 (all MFMA) + pool + GN3 stats -----
// (256,2) PERMANENT — (256,3) tested FIVE times (R10/R12/R14/R20 variants):
// spills at >84 arch need, occupancy collapse even when regs fit (R20).
// Bounce-free: GN epilogues write bf16 [pos][ch] tile; A-frags = ds_read_b128.
__global__ __launch_bounds__(256, 2) void k_main(
    const unsigned short* __restrict__ fused, const float* __restrict__ b1,
    const float* __restrict__ st1g, const float* __restrict__ g1,
    const float* __restrict__ be1, const unsigned short* __restrict__ wh1,
    const unsigned short* __restrict__ wh2, const float* __restrict__ b2,
    const float* __restrict__ A2, const float* __restrict__ B2,
    const unsigned short* __restrict__ wh3, const float* __restrict__ b3,
    unsigned short* __restrict__ zmx, unsigned short* __restrict__ zmn,
    float* __restrict__ st) {
  __shared__ unsigned short shbuf[4 * 64 * 104];   // 53KB shared stage/tile
  __shared__ float b1s[96], A1s[96], B1s[96], b2s[96], A2s[96], B2s[96], b3s[192];
  __shared__ float pmx[4][192], pmn[4][192];
  __shared__ float red[16];

  const int t = threadIdx.x, lane = t & 63, w = t >> 6;
  const int l15 = lane & 15, q = lane >> 4;
  const int b = blockIdx.x >> 9;
  const int n0 = (blockIdx.x & 511) << 2;

  unsigned short (*x0bf)[40] = (unsigned short(*)[40])shbuf;          // [260][40]
  unsigned short (*x1w)[104] = (unsigned short(*)[104])(shbuf + w * 64 * 104);

  // ---- stage x0 (bf16) + params
  {
    size_t fb = (size_t)b * 10 * PPB + (size_t)n0 * 64;
    for (int idx = t; idx < 256 * 11; idx += 256) {   // zero cols 10..31
      int R = idx / 11, u = 5 + idx % 11;
      *(unsigned*)&x0bf[R][u * 2] = 0u;
    }
    for (int idx = t; idx < 2560; idx += 256) {       // fill cols 0..9
      int c = idx >> 8, R = idx & 255;
      x0bf[R][c] = fused[fb + (size_t)c * PPB + R];
    }
    if (t < 96) {
      b1s[t] = b1[t];
      b2s[t] = b2[t];  A2s[t] = A2[b * 96 + t];  B2s[t] = B2[b * 96 + t];
      int g = t / 12;   // fused fin1
      float s = st1g[b * 16 + 2 * g], qq = st1g[b * 16 + 2 * g + 1];
      float mean = s * (1.0f / 1572864.0f);
      float var  = qq * (1.0f / 1572864.0f) - mean * mean;
      float r    = 1.0f / sqrtf(var + 1e-5f);
      float a    = g1[t] * r;
      A1s[t] = a; B1s[t] = be1[t] - mean * a;
    }
    if (t < 192) b3s[t] = b3[t];
    if (t < 16) red[t] = 0.f;
  }
  __syncthreads();

  // ---- load x0 A-frags (all waves), then shbuf becomes per-wave x1 tile
  bf8_t af0[4];
#pragma unroll
  for (int rt = 0; rt < 4; ++rt)
    af0[rt] = *(const bf8_t*)&x0bf[w * 64 + rt * 16 + l15][q * 8];
  __syncthreads();   // all af0 in regs before overwrite

  // ---- conv1 via MFMA -> GN1+relu -> x1 tile (bf16, [pos][ch])
#pragma unroll
  for (int nt = 0; nt < 6; ++nt) {
    bf8_t bh = *(const bf8_t*)(wh1 + (((nt << 6) + lane) << 3));
    f4_t ac[4];
#pragma unroll
    for (int rt = 0; rt < 4; ++rt) {
      ac[rt] = (f4_t){0.f, 0.f, 0.f, 0.f};
      ac[rt] = __builtin_amdgcn_mfma_f32_16x16x32_bf16(af0[rt], bh, ac[rt], 0, 0, 0);
    }
    const int ch = nt * 16 + l15;
    const float A = A1s[ch], Bb = B1s[ch], bi = b1s[ch];
#pragma unroll
    for (int rt = 0; rt < 4; ++rt)
#pragma unroll
      for (int r = 0; r < 4; ++r) {
        float x = A * (ac[rt][r] + bi) + Bb;
        x1w[rt * 16 + q * 4 + r][ch] = f2bf(x > 0.f ? x : 0.f);
      }
  }
  __builtin_amdgcn_wave_barrier();
  bf8_t a1[4][3];
#pragma unroll
  for (int rt = 0; rt < 4; ++rt)
#pragma unroll
    for (int ks = 0; ks < 3; ++ks)
      a1[rt][ks] = *(const bf8_t*)&x1w[rt * 16 + l15][ks * 32 + q * 8];
  __builtin_amdgcn_wave_barrier();

  // ---- conv2 -> GN2+relu -> x2 tile (overwrite; a1 fully in regs)
#pragma unroll
  for (int nt = 0; nt < 6; ++nt) {
    f4_t ac[4];
#pragma unroll
    for (int rt = 0; rt < 4; ++rt) ac[rt] = (f4_t){0.f, 0.f, 0.f, 0.f};
#pragma unroll
    for (int ks = 0; ks < 3; ++ks) {
      bf8_t bh = *(const bf8_t*)(wh2 + ((((ks * 6 + nt) << 6) + lane) << 3));
#pragma unroll
      for (int rt = 0; rt < 4; ++rt)
        ac[rt] = __builtin_amdgcn_mfma_f32_16x16x32_bf16(a1[rt][ks], bh, ac[rt], 0, 0, 0);
    }
    const int ch = nt * 16 + l15;
    const float A = A2s[ch], Bb = B2s[ch], bi = b2s[ch];
#pragma unroll
    for (int rt = 0; rt < 4; ++rt)
#pragma unroll
      for (int r = 0; r < 4; ++r) {
        float x = A * (ac[rt][r] + bi) + Bb;
        x1w[rt * 16 + q * 4 + r][ch] = f2bf(x > 0.f ? x : 0.f);
      }
  }
  __builtin_amdgcn_wave_barrier();
  bf8_t A3[4][3];
#pragma unroll
  for (int rt = 0; rt < 4; ++rt)
#pragma unroll
    for (int ks = 0; ks < 3; ++ks)
      A3[rt][ks] = *(const bf8_t*)&x1w[rt * 16 + l15][ks * 32 + q * 8];
  __builtin_amdgcn_wave_barrier();

  // ---- conv3 per output tile + pool + GN3 stats
  float sg[8], qg[8];
#pragma unroll
  for (int g = 0; g < 8; ++g) { sg[g] = 0.f; qg[g] = 0.f; }
#pragma unroll
  for (int nt = 0; nt < 12; ++nt) {
    f4_t ac[4];
#pragma unroll
    for (int rt = 0; rt < 4; ++rt) ac[rt] = (f4_t){0.f, 0.f, 0.f, 0.f};
#pragma unroll
    for (int ks = 0; ks < 3; ++ks) {
      bf8_t bh = *(const bf8_t*)(wh3 + ((((ks * 12 + nt) << 6) + lane) << 3));
#pragma unroll
      for (int rt = 0; rt < 4; ++rt)
        ac[rt] = __builtin_amdgcn_mfma_f32_16x16x32_bf16(A3[rt][ks], bh, ac[rt], 0, 0, 0);
    }
    int ch = nt * 16 + l15;
    float bi = b3s[ch];
    float s = 0.f, qq = 0.f, mx = -3.4e38f, mn = 3.4e38f;
#pragma unroll
    for (int rt = 0; rt < 4; ++rt) {
#pragma unroll
      for (int r = 0; r < 4; ++r) {
        float v = ac[rt][r] + bi;
        s += v; qq += v * v;
        mx = fmaxf(mx, v); mn = fminf(mn, v);
      }
    }
    mx = fmaxf(mx, __shfl_xor(mx, 16)); mx = fmaxf(mx, __shfl_xor(mx, 32));
    mn = fminf(mn, __shfl_xor(mn, 16)); mn = fminf(mn, __shfl_xor(mn, 32));
    if (lane < 16) { pmx[w][nt * 16 + lane] = mx; pmn[w][nt * 16 + lane] = mn; }
    const int g0 = (nt * 16) / 24;
    const int g1i = (nt * 16 + 15) / 24;
    if (g0 == g1i) {
      sg[g0] += s; qg[g0] += qq;
    } else {
      const int cut = g1i * 24 - nt * 16;
      if (l15 < cut) { sg[g0] += s; qg[g0] += qq; }
      else           { sg[g1i] += s; qg[g1i] += qq; }
    }
  }

#pragma unroll
  for (int g = 0; g < 8; ++g) {
#pragma unroll
    for (int off = 1; off < 64; off <<= 1) {
      sg[g] += __shfl_xor(sg[g], off);
      qg[g] += __shfl_xor(qg[g], off);
    }
  }
  if (lane == 0) {
#pragma unroll
    for (int g = 0; g < 8; ++g) {
      atomicAdd(&red[2 * g + 0], sg[g]);
      atomicAdd(&red[2 * g + 1], qg[g]);
    }
  }
  {
    int n = n0 + w;
    size_t ob = ((size_t)(b * NPTS + n)) * 192;
    for (int i = lane; i < 192; i += 64) {
      zmx[ob + i] = f2bf(pmx[w][i]);
      zmn[ob + i] = f2bf(pmn[w][i]);
    }
  }
  __syncthreads();
  if (t < 16) atomicAdd(&st[b * 16 + t], red[t]);
}

// ---------- K_post1 (MFMA): GN3+relu -> conv4 -> z4bf + GN4 stats ----------
__global__ __launch_bounds__(128) void k_post1(
    const unsigned short* __restrict__ zmx, const unsigned short* __restrict__ zmn,
    const float* __restrict__ st3, const float* __restrict__ g3,
    const float* __restrict__ be3, const unsigned short* __restrict__ wh4,
    const float* __restrict__ b4, unsigned short* __restrict__ z4bf,
    float* __restrict__ st4) {
  __shared__ unsigned short ybf[32][200];   // bf16 activations; reused as zbuf
  __shared__ float A3s[192], B3s[192], b4s[192];
  __shared__ float red[16];
  const int t = threadIdx.x, lane = t & 63, w = t >> 6;
  const int l15 = lane & 15, q = lane >> 4;
  const int p0 = blockIdx.x << 5;
  const int b = p0 >> 11;

  for (int c = t; c < 192; c += 128) {   // fused fin3
    int g = c / 24;
    float s = st3[b * 16 + 2 * g], qq = st3[b * 16 + 2 * g + 1];
    float mean = s * (1.0f / 3145728.0f);
    float var  = qq * (1.0f / 3145728.0f) - mean * mean;
    float r    = 1.0f / sqrtf(var + 1e-5f);
    float a    = g3[c] * r;
    A3s[c] = a; B3s[c] = be3[c] - mean * a; b4s[c] = b4[c];
  }
  if (t < 16) red[t] = 0.f;
  __syncthreads();

  for (int idx = t; idx < 32 * 192; idx += 128) {
    int ptl = idx / 192, ch = idx - ptl * 192;
    float A = A3s[ch];
    const unsigned short* src = (A > 0.f) ? zmx : zmn;
    float x = A * bf2f(src[(size_t)(p0 + ptl) * 192 + ch]) + B3s[ch];
    ybf[ptl][ch] = f2bf(x > 0.f ? x : 0.f);
  }
  __syncthreads();

  bf8_t af[6];
#pragma unroll
  for (int ks = 0; ks < 6; ++ks)
    af[ks] = *(const bf8_t*)&ybf[w * 16 + l15][ks * 32 + q * 8];
  __syncthreads();   // ybf free -> becomes zbuf

  float sg[8], qg[8];
#pragma unroll
  for (int g = 0; g < 8; ++g) { sg[g] = 0.f; qg[g] = 0.f; }
#pragma unroll
  for (int nt = 0; nt < 12; ++nt) {
    f4_t ac = (f4_t){0.f, 0.f, 0.f, 0.f};
#pragma unroll
    for (int ks = 0; ks < 6; ++ks) {
      bf8_t bh = *(const bf8_t*)(wh4 + ((((ks * 12 + nt) << 6) + lane) << 3));
      ac = __builtin_amdgcn_mfma_f32_16x16x32_bf16(af[ks], bh, ac, 0, 0, 0);
    }
    int ch = nt * 16 + l15;
    float bi = b4s[ch];
    float s = 0.f, qq = 0.f;
#pragma unroll
    for (int r = 0; r < 4; ++r) {
      float v = ac[r] + bi;
      s += v; qq += v * v;
      ybf[w * 16 + q * 4 + r][ch] = f2bf(v);   // zbuf (wave-private rows)
    }
    const int g0 = (nt * 16) / 24;
    const int g1i = (nt * 16 + 15) / 24;
    if (g0 == g1i) {
      sg[g0] += s; qg[g0] += qq;
    } else {
      const int cut = g1i * 24 - nt * 16;
      if (l15 < cut) { sg[g0] += s; qg[g0] += qq; }
      else           { sg[g1i] += s; qg[g1i] += qq; }
    }
  }
#pragma unroll
  for (int g = 0; g < 8; ++g) {
#pragma unroll
    for (int off = 1; off < 64; off <<= 1) {
      sg[g] += __shfl_xor(sg[g], off);
      qg[g] += __shfl_xor(qg[g], off);
    }
  }
  if (lane == 0) {
#pragma unroll
    for (int g = 0; g < 8; ++g) {
      atomicAdd(&red[2 * g + 0], sg[g]);
      atomicAdd(&red[2 * g + 1], qg[g]);
    }
  }
  __syncthreads();
  unsigned* z4u = (unsigned*)z4bf;
  for (int idx = t; idx < 32 * 96; idx += 128) {
    int ptl = idx / 96, pr = idx - ptl * 96;
    z4u[(size_t)(p0 + ptl) * 96 + pr] = *(const unsigned*)&ybf[ptl][pr * 2];
  }
  if (t < 16) atomicAdd(&st4[b * 16 + t], red[t]);
}

// ---------- K_post2 (MFMA): GN4+relu -> conv5 -> z5bf + GN5 stats ----------
__global__ __launch_bounds__(128) void k_post2(
    const unsigned short* __restrict__ z4bf, const float* __restrict__ st4,
    const float* __restrict__ g4, const float* __restrict__ be4,
    const unsigned short* __restrict__ wh5, const float* __restrict__ b5,
    unsigned short* __restrict__ z5bf, float* __restrict__ st5) {
  __shared__ unsigned short ybf[32][200];
  __shared__ float A4s[192], B4s[192], b5s[96];
  __shared__ float red[16];
  const int t = threadIdx.x, lane = t & 63, w = t >> 6;
  const int l15 = lane & 15, q = lane >> 4;
  const int p0 = blockIdx.x << 5;
  const int b = p0 >> 11;

  for (int c = t; c < 192; c += 128) {   // fused fin4 (count = 2048*24)
    int g = c / 24;
    float s = st4[b * 16 + 2 * g], qq = st4[b * 16 + 2 * g + 1];
    float mean = s * (1.0f / 49152.0f);
    float var  = qq * (1.0f / 49152.0f) - mean * mean;
    float r    = 1.0f / sqrtf(var + 1e-5f);
    float a    = g4[c] * r;
    A4s[c] = a; B4s[c] = be4[c] - mean * a;
  }
  if (t < 96) b5s[t] = b5[t];
  if (t < 16) red[t] = 0.f;
  __syncthreads();

  const unsigned* z4u = (const unsigned*)z4bf;
  for (int idx = t; idx < 32 * 96; idx += 128) {
    int ptl = idx / 96, pr = idx - ptl * 96;
    unsigned v = z4u[(size_t)(p0 + ptl) * 96 + pr];
    int ch = pr * 2;
    float x0 = A4s[ch] * bf2f((unsigned short)(v & 0xffff)) + B4s[ch];
    float x1 = A4s[ch + 1] * bf2f((unsigned short)(v >> 16)) + B4s[ch + 1];
    x0 = x0 > 0.f ? x0 : 0.f;
    x1 = x1 > 0.f ? x1 : 0.f;
    *(unsigned*)&ybf[ptl][ch] = cvt_pk_bf16(x0, x1);
  }
  __syncthreads();

  bf8_t af[6];
#pragma unroll
  for (int ks = 0; ks < 6; ++ks)
    af[ks] = *(const bf8_t*)&ybf[w * 16 + l15][ks * 32 + q * 8];
  __syncthreads();

  float sg[8], qg[8];
#pragma unroll
  for (int g = 0; g < 8; ++g) { sg[g] = 0.f; qg[g] = 0.f; }
#pragma unroll
  for (int nt = 0; nt < 6; ++nt) {
    f4_t ac = (f4_t){0.f, 0.f, 0.f, 0.f};
#pragma unroll
    for (int ks = 0; ks < 6; ++ks) {
      bf8_t bh = *(const bf8_t*)(wh5 + ((((ks * 6 + nt) << 6) + lane) << 3));
      ac = __builtin_amdgcn_mfma_f32_16x16x32_bf16(af[ks], bh, ac, 0, 0, 0);
    }
    int ch = nt * 16 + l15;
    float bi = b5s[ch];
    float s = 0.f, qq = 0.f;
#pragma unroll
    for (int r = 0; r < 4; ++r) {
      float v = ac[r] + bi;
      s += v; qq += v * v;
      ybf[w * 16 + q * 4 + r][ch] = f2bf(v);
    }
    const int g0 = (nt * 16) / 12;
    const int g1i = (nt * 16 + 15) / 12;
    const int cut = g1i * 12 - nt * 16;
    if (l15 < cut) { sg[g0] += s; qg[g0] += qq; }
    else           { sg[g1i] += s; qg[g1i] += qq; }
  }
#pragma unroll
  for (int g = 0; g < 8; ++g) {
#pragma unroll
    for (int off = 1; off < 64; off <<= 1) {
      sg[g] += __shfl_xor(sg[g], off);
      qg[g] += __shfl_xor(qg[g], off);
    }
  }
  if (lane == 0) {
#pragma unroll
    for (int g = 0; g < 8; ++g) {
      atomicAdd(&red[2 * g + 0], sg[g]);
      atomicAdd(&red[2 * g + 1], qg[g]);
    }
  }
  __syncthreads();
  unsigned* z5u = (unsigned*)z5bf;
  for (int idx = t; idx < 32 * 48; idx += 128) {
    int ptl = idx / 48, pr = idx - ptl * 48;
    z5u[(size_t)(p0 + ptl) * 48 + pr] = *(const unsigned*)&ybf[ptl][pr * 2];
  }
  if (t < 16) atomicAdd(&st5[b * 16 + t], red[t]);
}

// ------- K_post3 (f32, LDS weights): GN5+relu -> conv6 -> L2-norm -> out ---
__global__ __launch_bounds__(128) void k_post3(
    const unsigned short* __restrict__ z5bf, const float* __restrict__ st5,
    const float* __restrict__ g5, const float* __restrict__ be5,
    const float* __restrict__ w6, const float* __restrict__ b6,
    float* __restrict__ out) {
  __shared__ float y[32][100];        // f32 activations; reused as zs
  __shared__ float w6s[96][96];
  __shared__ float A5s[96], B5s[96], b6s[96];
  __shared__ float inv[32];
  const int t = threadIdx.x;
  const int ptl = t & 31, grp = t >> 5;
  const int p0 = blockIdx.x << 5;
  const int b = p0 >> 11;

  if (t < 96) {   // fused fin5 (count = 2048*12)
    int g = t / 12;
    float s = st5[b * 16 + 2 * g], qq = st5[b * 16 + 2 * g + 1];
    float mean = s * (1.0f / 24576.0f);
    float var  = qq * (1.0f / 24576.0f) - mean * mean;
    float r    = 1.0f / sqrtf(var + 1e-5f);
    float a    = g5[t] * r;
    A5s[t] = a; B5s[t] = be5[t] - mean * a; b6s[t] = b6[t];
  }
  for (int idx = t; idx < 9216; idx += 128)
    w6s[idx / 96][idx % 96] = w6[idx];
  __syncthreads();

  const unsigned* z5u = (const unsigned*)z5bf;
  for (int idx = t; idx < 32 * 48; idx += 128) {
    int pl = idx / 48, pr = idx - pl * 48;
    unsigned v = z5u[(size_t)(p0 + pl) * 48 + pr];
    int ch = pr * 2;
    float x0 = A5s[ch] * bf2f((unsigned short)(v & 0xffff)) + B5s[ch];
    float x1 = A5s[ch + 1] * bf2f((unsigned short)(v >> 16)) + B5s[ch + 1];
    y[pl][ch]     = x0 > 0.f ? x0 : 0.f;
    y[pl][ch + 1] = x1 > 0.f ? x1 : 0.f;
  }
  __syncthreads();

  const int ob = grp * 24;
  float z[24];
#pragma unroll
  for (int kb = 0; kb < 3; ++kb) {
    float a[8];
#pragma unroll
    for (int k = 0; k < 8; ++k) a[k] = b6s[ob + kb * 8 + k];
    for (int c4 = 0; c4 < 24; ++c4) {
      float4 xv = *(const float4*)&y[ptl][c4 * 4];
#pragma unroll
      for (int k = 0; k < 8; ++k) {
        const float* wr = &w6s[ob + kb * 8 + k][c4 * 4];
        a[k] += wr[0] * xv.x + wr[1] * xv.y + wr[2] * xv.z + wr[3] * xv.w;
      }
    }
#pragma unroll
    for (int k = 0; k < 8; ++k) z[kb * 8 + k] = a[k];
  }
  __syncthreads();   // all reads of y done -> reuse as zs
#pragma unroll
  for (int jj = 0; jj < 24; ++jj) y[ptl][ob + jj] = z[jj];
  __syncthreads();
  if (t < 32) {
    float ss = 0.f;
#pragma unroll
    for (int c = 0; c < 96; ++c) { float v = y[t][c]; ss += v * v; }
    float nf = (ss < 1e-20f) ? 0.0f : sqrtf(ss);
    inv[t] = 1.0f / nf;
  }
  __syncthreads();
  for (int idx = t; idx < 32 * 96; idx += 128) {
    int pl = idx / 96, ch = idx - pl * 96;
    out[(size_t)(p0 + pl) * 96 + ch] = y[pl][ch] * inv[pl];
  }
}

// --------------------------------------------------------------- launch ----
extern "C" void kernel_launch(void* const* d_in, const int* in_sizes, int n_in,
                              void* d_out, int out_size, void* d_ws, size_t ws_size,
                              hipStream_t stream) {
  (void)in_sizes; (void)n_in; (void)out_size; (void)ws_size;
  const float* xyz = (const float*)d_in[0];
  const float* nrm = (const float*)d_in[1];
  const float* w1 = (const float*)d_in[2];  const float* b1 = (const float*)d_in[3];
  const float* g1 = (const float*)d_in[4];  const float* be1 = (const float*)d_in[5];
  const float* w2 = (const float*)d_in[6];  const float* b2 = (const float*)d_in[7];
  const float* g2 = (const float*)d_in[8];  const float* be2 = (const float*)d_in[9];
  const float* w3 = (const float*)d_in[10]; const float* b3 = (const float*)d_in[11];
  const float* g3 = (const float*)d_in[12]; const float* be3 = (const float*)d_in[13];
  const float* w4 = (const float*)d_in[14]; const float* b4 = (const float*)d_in[15];
  const float* g4 = (const float*)d_in[16]; const float* be4 = (const float*)d_in[17];
  const float* w5 = (const float*)d_in[18]; const float* b5 = (const float*)d_in[19];
  const float* g5 = (const float*)d_in[20]; const float* be5 = (const float*)d_in[21];
  const float* w6 = (const float*)d_in[22]; const float* b6 = (const float*)d_in[23];

  float* ws = (float*)d_ws;
  unsigned short* fused = (unsigned short*)ws;   // 10,485,760 ushorts = 5,242,880 f
  unsigned short* zmxbf = (unsigned short*)(ws + 5242880);   // 3,145,728 ushorts
  unsigned short* zmnbf = zmxbf + 3145728;                   // 3,145,728 ushorts
  float* st1 = ws + 5242880 + 3145728;  //  128 each (after 2x1,572,864 f)
  float* st3 = st1 + 128;
  float* st4 = st3 + 128;
  float* st5 = st4 + 128;
  float* A2 = st5 + 128;  float* B2 = A2 + 768;
  float* wbuf = B2 + 768;               // bf16 frags: 86,016 ushorts = 43,008 f
  unsigned short* wh1 = (unsigned short*)wbuf;   //  3072
  unsigned short* wh2 = wh1 + 3072;              //  9216
  unsigned short* wh3 = wh2 + 9216;              // 18432
  unsigned short* wh4 = wh3 + 18432;             // 36864
  unsigned short* wh5 = wh4 + 36864;             // 18432
  float* G = wbuf + 43008;              // 8 x 12544 floats
  unsigned short* z4bf = (unsigned short*)(G + 100352);   // 3,145,728 ushorts
  unsigned short* z5bf = z4bf + 3145728;                  // 1,572,864 ushorts

  hipMemsetAsync(st1, 0, 4 * 128 * sizeof(float), stream);
  hipMemsetAsync(G, 0, 8 * 12544 * sizeof(float), stream);

  k_wprep <<<336, 256, 0, stream>>>(w1, w2, w3, w4, w5, wh1, wh2, wh3, wh4, wh5);
  k_feat  <<<4096, 256, 0, stream>>>(xyz, nrm, w1, b1, fused, st1);
  k_gram  <<<512, 256, 0, stream>>>(fused, wh1, b1, st1, g1, be1, G);
  k_fin2  <<<8, 384, 0, stream>>>(G, w2, b2, g2, be2, A2, B2);
  k_main  <<<4096, 256, 0, stream>>>(fused, b1, st1, g1, be1, wh1, wh2, b2, A2, B2,
                                     wh3, b3, zmxbf, zmnbf, st3);
  k_post1 <<<512, 128, 0, stream>>>(zmxbf, zmnbf, st3, g3, be3, wh4, b4, z4bf, st4);
  k_post2 <<<512, 128, 0, stream>>>(z4bf, st4, g4, be4, wh5, b5, z5bf, st5);
  k_post3 <<<512, 128, 0, stream>>>(z5bf, st5, g5, be5, w6, b6, (float*)d_out);
}

// Round 22
// 429.213 us; speedup vs baseline: 1.2747x; 1.0180x over previous
//
#include <hip/hip_runtime.h>
#include <math.h>

#define NPTS 2048
#define PPB  131072   // positions per batch = 2048 * 64

typedef __attribute__((ext_vector_type(8))) short bf8_t;   // 8 bf16 (4 VGPRs)
typedef __attribute__((ext_vector_type(4))) float f4_t;    // MFMA accumulator

__device__ __forceinline__ unsigned short f2bf(float x) {
  unsigned u = __float_as_uint(x);
  u += 0x7FFFu + ((u >> 16) & 1u);          // RNE
  return (unsigned short)(u >> 16);
}
__device__ __forceinline__ float bf2f(unsigned short h) {
  return __uint_as_float(((unsigned)h) << 16);
}
// 2 f32 -> packed 2xbf16 in one VALU op (low half = a, high half = b; RNE)
__device__ __forceinline__ unsigned cvt_pk_bf16(float a, float b) {
  unsigned r;
  asm("v_cvt_pk_bf16_f32 %0, %1, %2" : "=v"(r) : "v"(a), "v"(b));
  return r;
}

// ---------------------------------------------------------------- angle ----
__device__ __forceinline__ float angle_f(float ax, float ay, float az,
                                         float bx, float by, float bz) {
  float cx = ay * bz - az * by;
  float cy = az * bx - ax * bz;
  float cz = ax * by - ay * bx;
  float cn = cx * cx + cy * cy + cz * cz;
  float dt = ax * bx + ay * by + az * bz;
  bool  sml = cn < 1e-20f;
  bool  deg = sml && (fabsf(dt) < 1e-12f);
  float cns = sml ? 0.0f : sqrtf(cn);
  float ang = atan2f(cns, dt);
  return deg ? 0.0f : ang;
}

// --------------- weight prep: bf16 frags for conv1/2/3 and post1/2 --------
__global__ __launch_bounds__(256) void k_wprep(
    const float* __restrict__ w1, const float* __restrict__ w2,
    const float* __restrict__ w3, const float* __restrict__ w4,
    const float* __restrict__ w5,
    unsigned short* __restrict__ wh1, unsigned short* __restrict__ wh2,
    unsigned short* __restrict__ wh3, unsigned short* __restrict__ wh4,
    unsigned short* __restrict__ wh5) {
  int t = blockIdx.x * 256 + threadIdx.x;
  if (t < 3072) {            // conv1: 1 ks * 6 nt (96x10, K padded to 32)
    int i = t & 7, lane = (t >> 3) & 63, nt = t >> 9;
    int k = ((lane >> 4) << 3) + i;
    int n = nt * 16 + (lane & 15);
    wh1[t] = (k < 10) ? f2bf(w1[n * 10 + k]) : (unsigned short)0;
  } else if (t < 12288) {    // conv2: 3 ks * 6 nt (96x96)
    int f = t - 3072;
    int i = f & 7, lane = (f >> 3) & 63, r = f >> 9, nt = r % 6, ks = r / 6;
    int k = ks * 32 + ((lane >> 4) << 3) + i;
    int n = nt * 16 + (lane & 15);
    wh2[f] = f2bf(w2[n * 96 + k]);
  } else if (t < 30720) {    // conv3: 3 ks * 12 nt (192x96)
    int f = t - 12288;
    int i = f & 7, lane = (f >> 3) & 63, r = f >> 9, nt = r % 12, ks = r / 12;
    int k = ks * 32 + ((lane >> 4) << 3) + i;
    int n = nt * 16 + (lane & 15);
    wh3[f] = f2bf(w3[n * 96 + k]);
  } else if (t < 67584) {    // post1: 6 ks * 12 nt (192x192)
    int f = t - 30720;
    int i = f & 7, lane = (f >> 3) & 63, r = f >> 9, nt = r % 12, ks = r / 12;
    int k = ks * 32 + ((lane >> 4) << 3) + i;
    int n = nt * 16 + (lane & 15);
    wh4[f] = f2bf(w4[n * 192 + k]);
  } else if (t < 86016) {    // post2: 6 ks * 6 nt (96x192)
    int f = t - 67584;
    int i = f & 7, lane = (f >> 3) & 63, r = f >> 9, nt = r % 6, ks = r / 6;
    int k = ks * 32 + ((lane >> 4) << 3) + i;
    int n = nt * 16 + (lane & 15);
    wh5[f] = f2bf(w5[n * 192 + k]);
  }
}

// ---------------------------------------------------- K1: neighbors+feat ----
__global__ __launch_bounds__(256) void k_feat(
    const float* __restrict__ xyz, const float* __restrict__ nrm,
    const float* __restrict__ w1, const float* __restrict__ b1,
    unsigned short* __restrict__ fused, float* __restrict__ st) {
  const int wid = threadIdx.x >> 6, lane = threadIdx.x & 63;
  const int b = blockIdx.x >> 9;
  const int n = ((blockIdx.x & 511) << 2) + wid;
  const float* X  = xyz + (size_t)b * NPTS * 3;
  const float* NR = nrm + (size_t)b * NPTS * 3;
  __shared__ int   lst[4][64];
  __shared__ float red[16];

  const float xi0 = X[n * 3 + 0], xi1 = X[n * 3 + 1], xi2 = X[n * 3 + 2];

  int cnt = 0;
  for (int jb = 0; jb < NPTS; jb += 64) {
    int   j  = jb + lane;
    float dx = __fsub_rn(xi0, X[j * 3 + 0]);
    float dy = __fsub_rn(xi1, X[j * 3 + 1]);
    float dz = __fsub_rn(xi2, X[j * 3 + 2]);
    float sq = __fadd_rn(__fadd_rn(__fmul_rn(dx, dx), __fmul_rn(dy, dy)),
                         __fmul_rn(dz, dz));
    bool act = (sq <= 0.09f);
    unsigned long long m = __ballot(act);
    int pos = cnt + __popcll(m & ((1ull << lane) - 1ull));
    if (act && pos < 64) lst[wid][pos] = j;
    cnt += __popcll(m);
    if (cnt >= 64) break;
  }
  __syncthreads();

  const int j = lst[wid][(lane < cnt) ? lane : 0];

  const float gx = X[j * 3 + 0],  gy = X[j * 3 + 1],  gz = X[j * 3 + 2];
  const float gnx = NR[j * 3 + 0], gny = NR[j * 3 + 1], gnz = NR[j * 3 + 2];
  const float nix = NR[n * 3 + 0], niy = NR[n * 3 + 1], niz = NR[n * 3 + 2];
  const float dx = gx - xi0, dy = gy - xi1, dz = gz - xi2;

  float f[10];
  f[0] = xi0; f[1] = xi1; f[2] = xi2;
  f[3] = dx;  f[4] = dy;  f[5] = dz;
  f[6] = angle_f(nix, niy, niz, dx, dy, dz);
  f[7] = angle_f(gnx, gny, gnz, dx, dy, dz);
  f[8] = angle_f(nix, niy, niz, gnx, gny, gnz);
  float ss = dx * dx + dy * dy + dz * dz;
  f[9] = (ss < 1e-20f) ? 0.0f : sqrtf(ss);

  size_t base = (size_t)b * 10 * PPB + (size_t)n * 64 + lane;
#pragma unroll
  for (int c = 0; c < 10; ++c) fused[base + (size_t)c * PPB] = f2bf(f[c]);

  float sg[8], qg[8];
#pragma unroll
  for (int g = 0; g < 8; ++g) {
    float s = 0.f, q = 0.f;
#pragma unroll
    for (int t2 = 0; t2 < 12; ++t2) {
      const int o = g * 12 + t2;
      float a = b1[o];
#pragma unroll
      for (int c = 0; c < 10; ++c) a += w1[o * 10 + c] * f[c];
      s += a; q += a * a;
    }
    sg[g] = s; qg[g] = q;
  }
#pragma unroll
  for (int g = 0; g < 8; ++g) {
#pragma unroll
    for (int off = 32; off; off >>= 1) {
      sg[g] += __shfl_xor(sg[g], off);
      qg[g] += __shfl_xor(qg[g], off);
    }
  }
  if (threadIdx.x < 16) red[threadIdx.x] = 0.f;
  __syncthreads();
  if (lane == 0) {
#pragma unroll
    for (int g = 0; g < 8; ++g) {
      atomicAdd(&red[2 * g + 0], sg[g]);
      atomicAdd(&red[2 * g + 1], qg[g]);
    }
  }
  __syncthreads();
  if (threadIdx.x < 16) atomicAdd(&st[b * 16 + threadIdx.x], red[threadIdx.x]);
}

// ---------------------- K_gram: conv1 (MFMA) -> x1, G = sum x1~ x1~^T ------
// R22: conv1 epilogue packs 4 consecutive pos (contiguous in [ch][pos] tile)
// via cvt_pk + b64 write — bit-identical to f2bf (both RNE).
#define GRAM_TILE(i, MT, NT) \
  acc[i] = __builtin_amdgcn_mfma_f32_16x16x32_bf16(fh##MT, fh##NT, acc[i], 0, 0, 0);
#define GRAM_LD(T) \
  bf8_t fh##T = *(const bf8_t*)&x1h[pp][T * 16 + l15][ko];
#define GRAM_OUT(i, MT, NT) do { \
  _Pragma("unroll") \
  for (int r = 0; r < 4; ++r) \
    atomicAdd(&Gb[(MT * 16 + q * 4 + r) * 112 + NT * 16 + l15], acc[i][r]); \
} while (0)

__global__ __launch_bounds__(256) void k_gram(
    const unsigned short* __restrict__ fused, const unsigned short* __restrict__ wh1,
    const float* __restrict__ b1, const float* __restrict__ st1g,
    const float* __restrict__ g1, const float* __restrict__ be1,
    float* __restrict__ G) {
  __shared__ unsigned short x1h[2][112][72];
  __shared__ unsigned short x0bf[128][40];   // bf16 x0, K-padded (2 points)
  __shared__ float A1s[96], B1s[96], b1s[96];
  const int t = threadIdx.x, lane = t & 63, w = t >> 6;
  const int l15 = lane & 15, q = lane >> 4;
  const int b = blockIdx.x >> 6;          // 512 blocks = 8 batches x 64
  const int blk = blockIdx.x & 63;        // 32 points each (16 iters x 2)

  if (t < 96) {   // fused fin1
    int g = t / 12;
    float s = st1g[b * 16 + 2 * g], qq = st1g[b * 16 + 2 * g + 1];
    float mean = s * (1.0f / 1572864.0f);
    float var  = qq * (1.0f / 1572864.0f) - mean * mean;
    float r    = 1.0f / sqrtf(var + 1e-5f);
    float a    = g1[t] * r;
    A1s[t] = a; B1s[t] = be1[t] - mean * a; b1s[t] = b1[t];
  }
  for (int idx = t; idx < 2 * 16 * 72; idx += 256) {  // ones row 96, zeros 97..111
    int pp = idx / (16 * 72), rem = idx % (16 * 72);
    int ch = 96 + rem / 72, rr = rem % 72;
    x1h[pp][ch][rr] = (ch == 96) ? (unsigned short)0x3F80 : (unsigned short)0;
  }
  __syncthreads();

  f4_t acc[7];
#pragma unroll
  for (int i = 0; i < 7; ++i) acc[i] = (f4_t){0.f, 0.f, 0.f, 0.f};

  for (int it = 0; it < 16; ++it) {
    int n = blk * 32 + it * 2;
    size_t fb = (size_t)b * 10 * PPB + (size_t)n * 64;
    __syncthreads();   // prior Gram reads done before overwrite
    for (int idx = t; idx < 128 * 11; idx += 256) {  // zero cols 10..31
      int R = idx / 11, u = 5 + idx % 11;
      *(unsigned*)&x0bf[R][u * 2] = 0u;
    }
    for (int idx = t; idx < 1280; idx += 256) {      // fill cols 0..9 (2 pts)
      int c = idx >> 7, s = idx & 127;
      x0bf[s][c] = fused[fb + (size_t)c * PPB + s];
    }
    __syncthreads();
    // conv1 via MFMA for both points: wave w owns rows w*16..w*16+15 of each
#pragma unroll
    for (int pp = 0; pp < 2; ++pp) {
      bf8_t af0 = *(const bf8_t*)&x0bf[pp * 64 + w * 16 + l15][q * 8];
#pragma unroll
      for (int nt = 0; nt < 6; ++nt) {
        f4_t a1c = (f4_t){0.f, 0.f, 0.f, 0.f};
        bf8_t bh = *(const bf8_t*)(wh1 + (((nt << 6) + lane) << 3));
        a1c = __builtin_amdgcn_mfma_f32_16x16x32_bf16(af0, bh, a1c, 0, 0, 0);
        const int ch = nt * 16 + l15;
        const float A = A1s[ch], Bb = B1s[ch], bi = b1s[ch];
        float x0 = A * (a1c[0] + bi) + Bb; x0 = x0 > 0.f ? x0 : 0.f;
        float x1 = A * (a1c[1] + bi) + Bb; x1 = x1 > 0.f ? x1 : 0.f;
        float x2 = A * (a1c[2] + bi) + Bb; x2 = x2 > 0.f ? x2 : 0.f;
        float x3 = A * (a1c[3] + bi) + Bb; x3 = x3 > 0.f ? x3 : 0.f;
        uint2 pk;
        pk.x = cvt_pk_bf16(x0, x1);
        pk.y = cvt_pk_bf16(x2, x3);
        *(uint2*)&x1h[pp][ch][w * 16 + q * 4] = pk;
      }
    }
    __syncthreads();
#pragma unroll
    for (int pp = 0; pp < 2; ++pp) {
#pragma unroll
      for (int ksr = 0; ksr < 2; ++ksr) {
        const int ko = ksr * 32 + q * 8;
        GRAM_LD(0) GRAM_LD(1) GRAM_LD(2) GRAM_LD(3) GRAM_LD(4) GRAM_LD(5) GRAM_LD(6)
        if (w == 0) {
          GRAM_TILE(0, 0, 0); GRAM_TILE(1, 0, 1); GRAM_TILE(2, 0, 2);
          GRAM_TILE(3, 0, 3); GRAM_TILE(4, 0, 4); GRAM_TILE(5, 0, 5); GRAM_TILE(6, 0, 6);
        } else if (w == 1) {
          GRAM_TILE(0, 1, 1); GRAM_TILE(1, 1, 2); GRAM_TILE(2, 1, 3);
          GRAM_TILE(3, 1, 4); GRAM_TILE(4, 1, 5); GRAM_TILE(5, 1, 6); GRAM_TILE(6, 2, 2);
        } else if (w == 2) {
          GRAM_TILE(0, 2, 3); GRAM_TILE(1, 2, 4); GRAM_TILE(2, 2, 5);
          GRAM_TILE(3, 2, 6); GRAM_TILE(4, 3, 3); GRAM_TILE(5, 3, 4); GRAM_TILE(6, 3, 5);
        } else {
          GRAM_TILE(0, 3, 6); GRAM_TILE(1, 4, 4); GRAM_TILE(2, 4, 5);
          GRAM_TILE(3, 4, 6); GRAM_TILE(4, 5, 5); GRAM_TILE(5, 5, 6); GRAM_TILE(6, 6, 6);
        }
      }
    }
  }
  float* Gb = G + (size_t)b * 12544;
  if (w == 0) {
    GRAM_OUT(0, 0, 0); GRAM_OUT(1, 0, 1); GRAM_OUT(2, 0, 2);
    GRAM_OUT(3, 0, 3); GRAM_OUT(4, 0, 4); GRAM_OUT(5, 0, 5); GRAM_OUT(6, 0, 6);
  } else if (w == 1) {
    GRAM_OUT(0, 1, 1); GRAM_OUT(1, 1, 2); GRAM_OUT(2, 1, 3);
    GRAM_OUT(3, 1, 4); GRAM_OUT(4, 1, 5); GRAM_OUT(5, 1, 6); GRAM_OUT(6, 2, 2);
  } else if (w == 2) {
    GRAM_OUT(0, 2, 3); GRAM_OUT(1, 2, 4); GRAM_OUT(2, 2, 5);
    GRAM_OUT(3, 2, 6); GRAM_OUT(4, 3, 3); GRAM_OUT(5, 3, 4); GRAM_OUT(6, 3, 5);
  } else {
    GRAM_OUT(0, 3, 6); GRAM_OUT(1, 4, 4); GRAM_OUT(2, 4, 5);
    GRAM_OUT(3, 4, 6); GRAM_OUT(4, 5, 5); GRAM_OUT(5, 5, 6); GRAM_OUT(6, 6, 6);
  }
}

// ------------------- K_fin2: GN2 params from Gram (parallelized) -----------
__global__ void k_fin2(const float* __restrict__ G, const float* __restrict__ w2,
                       const float* __restrict__ b2, const float* __restrict__ gm,
                       const float* __restrict__ bt, float* __restrict__ A2,
                       float* __restrict__ B2) {
  __shared__ float Gs[96][97];
  __shared__ float s1s[96], cs[96], cq[96];
  __shared__ float qp[96][4];
  __shared__ float gsum[8][2];
  const int b = blockIdx.x, t = threadIdx.x;   // 384 threads
  const int ch = t % 96, p = t / 96;
  for (int idx = t; idx < 9216; idx += 384) {
    int i = idx / 96, j = idx - i * 96;
    Gs[i][j] = ((i >> 4) <= (j >> 4)) ? G[b * 12544 + i * 112 + j]
                                      : G[b * 12544 + j * 112 + i];
  }
  if (t < 96) s1s[t] = G[b * 12544 + t * 112 + 96];
  __syncthreads();
  float wrow[96];
#pragma unroll
  for (int k = 0; k < 96; ++k) wrow[k] = w2[ch * 96 + k];
  float part = 0.f;
  for (int i = p * 24; i < p * 24 + 24; ++i) {
    float gi = 0.f;
#pragma unroll
    for (int jj = 0; jj < 96; ++jj) gi += Gs[i][jj] * wrow[jj];
    part += wrow[i] * gi;
  }
  qp[ch][p] = part;
  __syncthreads();
  if (t < 96) {
    float ds = 0.f;
#pragma unroll
    for (int k = 0; k < 96; ++k) ds += wrow[k] * s1s[k];
    float qf = qp[t][0] + qp[t][1] + qp[t][2] + qp[t][3];
    const float P = 131072.0f;
    cs[t] = ds + P * b2[t];
    cq[t] = qf + 2.0f * b2[t] * ds + P * b2[t] * b2[t];
  }
  __syncthreads();
  if (t < 8) {
    float s = 0.f, qq = 0.f;
    for (int k = 0; k < 12; ++k) { s += cs[t * 12 + k]; qq += cq[t * 12 + k]; }
    gsum[t][0] = s; gsum[t][1] = qq;
  }
  __syncthreads();
  if (t < 96) {
    int g = t / 12;
    float mean = gsum[g][0] * (1.0f / 1572864.0f);
    float var  = gsum[g][1] * (1.0f / 1572864.0f) - mean * mean;
    float r    = 1.0f / sqrtf(var + 1e-5f);
    float a    = gm[t] * r;
    A2[b * 96 + t] = a;
    B2[b * 96 + t] = bt[t] - mean * a;
  }
}

// ------------- K_main: conv1+conv2+conv3 (all MFMA) + pool + GN3 stats -----
// (256,2) PERMANENT — (256,3) tested FIVE times: closed.
// R22: conv1/conv2 MFMA operands SWAPPED (mfma(weights, acts)) so each thread
// holds 4 consecutive CH for one POS -> contiguous 8B in [pos][ch] tile:
// epilogue = 2 cvt_pk + 1 b64 write (was 16 f2bf + 16 ushort stores).
// conv3 unswapped (register-only epilogue feeds pool/stats reduction).
__global__ __launch_bounds__(256, 2) void k_main(
    const unsigned short* __restrict__ fused, const float* __restrict__ b1,
    const float* __restrict__ st1g, const float* __restrict__ g1,
    const float* __restrict__ be1, const unsigned short* __restrict__ wh1,
    const unsigned short* __restrict__ wh2, const float* __restrict__ b2,
    const float* __restrict__ A2, const float* __restrict__ B2,
    const unsigned short* __restrict__ wh3, const float* __restrict__ b3,
    unsigned short* __restrict__ zmx, unsigned short* __restrict__ zmn,
    float* __restrict__ st) {
  __shared__ unsigned short shbuf[4 * 64 * 104];   // 53KB shared stage/tile
  __shared__ float b1s[96], A1s[96], B1s[96], b2s[96], A2s[96], B2s[96], b3s[192];
  __shared__ float pmx[4][192], pmn[4][192];
  __shared__ float red[16];

  const int t = threadIdx.x, lane = t & 63, w = t >> 6;
  const int l15 = lane & 15, q = lane >> 4;
  const int b = blockIdx.x >> 9;
  const int n0 = (blockIdx.x & 511) << 2;

  unsigned short (*x0bf)[40] = (unsigned short(*)[40])shbuf;          // [260][40]
  unsigned short (*x1w)[104] = (unsigned short(*)[104])(shbuf + w * 64 * 104);

  // ---- stage x0 (bf16) + params
  {
    size_t fb = (size_t)b * 10 * PPB + (size_t)n0 * 64;
    for (int idx = t; idx < 256 * 11; idx += 256) {   // zero cols 10..31
      int R = idx / 11, u = 5 + idx % 11;
      *(unsigned*)&x0bf[R][u * 2] = 0u;
    }
    for (int idx = t; idx < 2560; idx += 256) {       // fill cols 0..9
      int c = idx >> 8, R = idx & 255;
      x0bf[R][c] = fused[fb + (size_t)c * PPB + R];
    }
    if (t < 96) {
      b1s[t] = b1[t];
      b2s[t] = b2[t];  A2s[t] = A2[b * 96 + t];  B2s[t] = B2[b * 96 + t];
      int g = t / 12;   // fused fin1
      float s = st1g[b * 16 + 2 * g], qq = st1g[b * 16 + 2 * g + 1];
      float mean = s * (1.0f / 1572864.0f);
      float var  = qq * (1.0f / 1572864.0f) - mean * mean;
      float r    = 1.0f / sqrtf(var + 1e-5f);
      float a    = g1[t] * r;
      A1s[t] = a; B1s[t] = be1[t] - mean * a;
    }
    if (t < 192) b3s[t] = b3[t];
    if (t < 16) red[t] = 0.f;
  }
  __syncthreads();

  // ---- load x0 A-frags (all waves), then shbuf becomes per-wave x1 tile
  bf8_t af0[4];
#pragma unroll
  for (int rt = 0; rt < 4; ++rt)
    af0[rt] = *(const bf8_t*)&x0bf[w * 64 + rt * 16 + l15][q * 8];
  __syncthreads();   // all af0 in regs before overwrite

  // ---- conv1 via MFMA (SWAPPED: weights first) -> GN1+relu -> x1 tile
#pragma unroll
  for (int nt = 0; nt < 6; ++nt) {
    bf8_t bh = *(const bf8_t*)(wh1 + (((nt << 6) + lane) << 3));
    f4_t ac[4];
#pragma unroll
    for (int rt = 0; rt < 4; ++rt) {
      ac[rt] = (f4_t){0.f, 0.f, 0.f, 0.f};
      ac[rt] = __builtin_amdgcn_mfma_f32_16x16x32_bf16(bh, af0[rt], ac[rt], 0, 0, 0);
    }
    const int ch0 = nt * 16 + q * 4;
    const float4 Af = *(const float4*)&A1s[ch0];
    const float4 Bf = *(const float4*)&B1s[ch0];
    const float4 bf = *(const float4*)&b1s[ch0];
#pragma unroll
    for (int rt = 0; rt < 4; ++rt) {
      float x0 = Af.x * (ac[rt][0] + bf.x) + Bf.x; x0 = x0 > 0.f ? x0 : 0.f;
      float x1 = Af.y * (ac[rt][1] + bf.y) + Bf.y; x1 = x1 > 0.f ? x1 : 0.f;
      float x2 = Af.z * (ac[rt][2] + bf.z) + Bf.z; x2 = x2 > 0.f ? x2 : 0.f;
      float x3 = Af.w * (ac[rt][3] + bf.w) + Bf.w; x3 = x3 > 0.f ? x3 : 0.f;
      uint2 pk;
      pk.x = cvt_pk_bf16(x0, x1);
      pk.y = cvt_pk_bf16(x2, x3);
      *(uint2*)&x1w[rt * 16 + l15][ch0] = pk;
    }
  }
  __builtin_amdgcn_wave_barrier();
  bf8_t a1[4][3];
#pragma unroll
  for (int rt = 0; rt < 4; ++rt)
#pragma unroll
    for (int ks = 0; ks < 3; ++ks)
      a1[rt][ks] = *(const bf8_t*)&x1w[rt * 16 + l15][ks * 32 + q * 8];
  __builtin_amdgcn_wave_barrier();

  // ---- conv2 (SWAPPED) -> GN2+relu -> x2 tile (overwrite; a1 in regs)
#pragma unroll
  for (int nt = 0; nt < 6; ++nt) {
    f4_t ac[4];
#pragma unroll
    for (int rt = 0; rt < 4; ++rt) ac[rt] = (f4_t){0.f, 0.f, 0.f, 0.f};
#pragma unroll
    for (int ks = 0; ks < 3; ++ks) {
      bf8_t bh = *(const bf8_t*)(wh2 + ((((ks * 6 + nt) << 6) + lane) << 3));
#pragma unroll
      for (int rt = 0; rt < 4; ++rt)
        ac[rt] = __builtin_amdgcn_mfma_f32_16x16x32_bf16(bh, a1[rt][ks], ac[rt], 0, 0, 0);
    }
    const int ch0 = nt * 16 + q * 4;
    const float4 Af = *(const float4*)&A2s[ch0];
    const float4 Bf = *(const float4*)&B2s[ch0];
    const float4 bf = *(const float4*)&b2s[ch0];
#pragma unroll
    for (int rt = 0; rt < 4; ++rt) {
      float x0 = Af.x * (ac[rt][0] + bf.x) + Bf.x; x0 = x0 > 0.f ? x0 : 0.f;
      float x1 = Af.y * (ac[rt][1] + bf.y) + Bf.y; x1 = x1 > 0.f ? x1 : 0.f;
      float x2 = Af.z * (ac[rt][2] + bf.z) + Bf.z; x2 = x2 > 0.f ? x2 : 0.f;
      float x3 = Af.w * (ac[rt][3] + bf.w) + Bf.w; x3 = x3 > 0.f ? x3 : 0.f;
      uint2 pk;
      pk.x = cvt_pk_bf16(x0, x1);
      pk.y = cvt_pk_bf16(x2, x3);
      *(uint2*)&x1w[rt * 16 + l15][ch0] = pk;
    }
  }
  __builtin_amdgcn_wave_barrier();
  bf8_t A3[4][3];
#pragma unroll
  for (int rt = 0; rt < 4; ++rt)
#pragma unroll
    for (int ks = 0; ks < 3; ++ks)
      A3[rt][ks] = *(const bf8_t*)&x1w[rt * 16 + l15][ks * 32 + q * 8];
  __builtin_amdgcn_wave_barrier();

  // ---- conv3 per output tile + pool + GN3 stats (UNSWAPPED)
  float sg[8], qg[8];
#pragma unroll
  for (int g = 0; g < 8; ++g) { sg[g] = 0.f; qg[g] = 0.f; }
#pragma unroll
  for (int nt = 0; nt < 12; ++nt) {
    f4_t ac[4];
#pragma unroll
    for (int rt = 0; rt < 4; ++rt) ac[rt] = (f4_t){0.f, 0.f, 0.f, 0.f};
#pragma unroll
    for (int ks = 0; ks < 3; ++ks) {
      bf8_t bh = *(const bf8_t*)(wh3 + ((((ks * 12 + nt) << 6) + lane) << 3));
#pragma unroll
      for (int rt = 0; rt < 4; ++rt)
        ac[rt] = __builtin_amdgcn_mfma_f32_16x16x32_bf16(A3[rt][ks], bh, ac[rt], 0, 0, 0);
    }
    int ch = nt * 16 + l15;
    float bi = b3s[ch];
    float s = 0.f, qq = 0.f, mx = -3.4e38f, mn = 3.4e38f;
#pragma unroll
    for (int rt = 0; rt < 4; ++rt) {
#pragma unroll
      for (int r = 0; r < 4; ++r) {
        float v = ac[rt][r] + bi;
        s += v; qq += v * v;
        mx = fmaxf(mx, v); mn = fminf(mn, v);
      }
    }
    mx = fmaxf(mx, __shfl_xor(mx, 16)); mx = fmaxf(mx, __shfl_xor(mx, 32));
    mn = fminf(mn, __shfl_xor(mn, 16)); mn = fminf(mn, __shfl_xor(mn, 32));
    if (lane < 16) { pmx[w][nt * 16 + lane] = mx; pmn[w][nt * 16 + lane] = mn; }
    const int g0 = (nt * 16) / 24;
    const int g1i = (nt * 16 + 15) / 24;
    if (g0 == g1i) {
      sg[g0] += s; qg[g0] += qq;
    } else {
      const int cut = g1i * 24 - nt * 16;
      if (l15 < cut) { sg[g0] += s; qg[g0] += qq; }
      else           { sg[g1i] += s; qg[g1i] += qq; }
    }
  }

#pragma unroll
  for (int g = 0; g < 8; ++g) {
#pragma unroll
    for (int off = 1; off < 64; off <<= 1) {
      sg[g] += __shfl_xor(sg[g], off);
      qg[g] += __shfl_xor(qg[g], off);
    }
  }
  if (lane == 0) {
#pragma unroll
    for (int g = 0; g < 8; ++g) {
      atomicAdd(&red[2 * g + 0], sg[g]);
      atomicAdd(&red[2 * g + 1], qg[g]);
    }
  }
  {
    int n = n0 + w;
    size_t ob = ((size_t)(b * NPTS + n)) * 192;
    for (int i = lane; i < 192; i += 64) {
      zmx[ob + i] = f2bf(pmx[w][i]);
      zmn[ob + i] = f2bf(pmn[w][i]);
    }
  }
  __syncthreads();
  if (t < 16) atomicAdd(&st[b * 16 + t], red[t]);
}

// ---------- K_post1 (MFMA): GN3+relu -> conv4 -> z4bf + GN4 stats ----------
__global__ __launch_bounds__(128) void k_post1(
    const unsigned short* __restrict__ zmx, const unsigned short* __restrict__ zmn,
    const float* __restrict__ st3, const float* __restrict__ g3,
    const float* __restrict__ be3, const unsigned short* __restrict__ wh4,
    const float* __restrict__ b4, unsigned short* __restrict__ z4bf,
    float* __restrict__ st4) {
  __shared__ unsigned short ybf[32][200];   // bf16 activations; reused as zbuf
  __shared__ float A3s[192], B3s[192], b4s[192];
  __shared__ float red[16];
  const int t = threadIdx.x, lane = t & 63, w = t >> 6;
  const int l15 = lane & 15, q = lane >> 4;
  const int p0 = blockIdx.x << 5;
  const int b = p0 >> 11;

  for (int c = t; c < 192; c += 128) {   // fused fin3
    int g = c / 24;
    float s = st3[b * 16 + 2 * g], qq = st3[b * 16 + 2 * g + 1];
    float mean = s * (1.0f / 3145728.0f);
    float var  = qq * (1.0f / 3145728.0f) - mean * mean;
    float r    = 1.0f / sqrtf(var + 1e-5f);
    float a    = g3[c] * r;
    A3s[c] = a; B3s[c] = be3[c] - mean * a; b4s[c] = b4[c];
  }
  if (t < 16) red[t] = 0.f;
  __syncthreads();

  for (int idx = t; idx < 32 * 192; idx += 128) {
    int ptl = idx / 192, ch = idx - ptl * 192;
    float A = A3s[ch];
    const unsigned short* src = (A > 0.f) ? zmx : zmn;
    float x = A * bf2f(src[(size_t)(p0 + ptl) * 192 + ch]) + B3s[ch];
    ybf[ptl][ch] = f2bf(x > 0.f ? x : 0.f);
  }
  __syncthreads();

  bf8_t af[6];
#pragma unroll
  for (int ks = 0; ks < 6; ++ks)
    af[ks] = *(const bf8_t*)&ybf[w * 16 + l15][ks * 32 + q * 8];
  __syncthreads();   // ybf free -> becomes zbuf

  float sg[8], qg[8];
#pragma unroll
  for (int g = 0; g < 8; ++g) { sg[g] = 0.f; qg[g] = 0.f; }
#pragma unroll
  for (int nt = 0; nt < 12; ++nt) {
    f4_t ac = (f4_t){0.f, 0.f, 0.f, 0.f};
#pragma unroll
    for (int ks = 0; ks < 6; ++ks) {
      bf8_t bh = *(const bf8_t*)(wh4 + ((((ks * 12 + nt) << 6) + lane) << 3));
      ac = __builtin_amdgcn_mfma_f32_16x16x32_bf16(af[ks], bh, ac, 0, 0, 0);
    }
    int ch = nt * 16 + l15;
    float bi = b4s[ch];
    float s = 0.f, qq = 0.f;
#pragma unroll
    for (int r = 0; r < 4; ++r) {
      float v = ac[r] + bi;
      s += v; qq += v * v;
      ybf[w * 16 + q * 4 + r][ch] = f2bf(v);   // zbuf (wave-private rows)
    }
    const int g0 = (nt * 16) / 24;
    const int g1i = (nt * 16 + 15) / 24;
    if (g0 == g1i) {
      sg[g0] += s; qg[g0] += qq;
    } else {
      const int cut = g1i * 24 - nt * 16;
      if (l15 < cut) { sg[g0] += s; qg[g0] += qq; }
      else           { sg[g1i] += s; qg[g1i] += qq; }
    }
  }
#pragma unroll
  for (int g = 0; g < 8; ++g) {
#pragma unroll
    for (int off = 1; off < 64; off <<= 1) {
      sg[g] += __shfl_xor(sg[g], off);
      qg[g] += __shfl_xor(qg[g], off);
    }
  }
  if (lane == 0) {
#pragma unroll
    for (int g = 0; g < 8; ++g) {
      atomicAdd(&red[2 * g + 0], sg[g]);
      atomicAdd(&red[2 * g + 1], qg[g]);
    }
  }
  __syncthreads();
  unsigned* z4u = (unsigned*)z4bf;
  for (int idx = t; idx < 32 * 96; idx += 128) {
    int ptl = idx / 96, pr = idx - ptl * 96;
    z4u[(size_t)(p0 + ptl) * 96 + pr] = *(const unsigned*)&ybf[ptl][pr * 2];
  }
  if (t < 16) atomicAdd(&st4[b * 16 + t], red[t]);
}

// ---------- K_post2 (MFMA): GN4+relu -> conv5 -> z5bf + GN5 stats ----------
__global__ __launch_bounds__(128) void k_post2(
    const unsigned short* __restrict__ z4bf, const float* __restrict__ st4,
    const float* __restrict__ g4, const float* __restrict__ be4,
    const unsigned short* __restrict__ wh5, const float* __restrict__ b5,
    unsigned short* __restrict__ z5bf, float* __restrict__ st5) {
  __shared__ unsigned short ybf[32][200];
  __shared__ float A4s[192], B4s[192], b5s[96];
  __shared__ float red[16];
  const int t = threadIdx.x, lane = t & 63, w = t >> 6;
  const int l15 = lane & 15, q = lane >> 4;
  const int p0 = blockIdx.x << 5;
  const int b = p0 >> 11;

  for (int c = t; c < 192; c += 128) {   // fused fin4 (count = 2048*24)
    int g = c / 24;
    float s = st4[b * 16 + 2 * g], qq = st4[b * 16 + 2 * g + 1];
    float mean = s * (1.0f / 49152.0f);
    float var  = qq * (1.0f / 49152.0f) - mean * mean;
    float r    = 1.0f / sqrtf(var + 1e-5f);
    float a    = g4[c] * r;
    A4s[c] = a; B4s[c] = be4[c] - mean * a;
  }
  if (t < 96) b5s[t] = b5[t];
  if (t < 16) red[t] = 0.f;
  __syncthreads();

  const unsigned* z4u = (const unsigned*)z4bf;
  for (int idx = t; idx < 32 * 96; idx += 128) {
    int ptl = idx / 96, pr = idx - ptl * 96;
    unsigned v = z4u[(size_t)(p0 + ptl) * 96 + pr];
    int ch = pr * 2;
    float x0 = A4s[ch] * bf2f((unsigned short)(v & 0xffff)) + B4s[ch];
    float x1 = A4s[ch + 1] * bf2f((unsigned short)(v >> 16)) + B4s[ch + 1];
    x0 = x0 > 0.f ? x0 : 0.f;
    x1 = x1 > 0.f ? x1 : 0.f;
    *(unsigned*)&ybf[ptl][ch] = cvt_pk_bf16(x0, x1);
  }
  __syncthreads();

  bf8_t af[6];
#pragma unroll
  for (int ks = 0; ks < 6; ++ks)
    af[ks] = *(const bf8_t*)&ybf[w * 16 + l15][ks * 32 + q * 8];
  __syncthreads();

  float sg[8], qg[8];
#pragma unroll
  for (int g = 0; g < 8; ++g) { sg[g] = 0.f; qg[g] = 0.f; }
#pragma unroll
  for (int nt = 0; nt < 6; ++nt) {
    f4_t ac = (f4_t){0.f, 0.f, 0.f, 0.f};
#pragma unroll
    for (int ks = 0; ks < 6; ++ks) {
      bf8_t bh = *(const bf8_t*)(wh5 + ((((ks * 6 + nt) << 6) + lane) << 3));
      ac = __builtin_amdgcn_mfma_f32_16x16x32_bf16(af[ks], bh, ac, 0, 0, 0);
    }
    int ch = nt * 16 + l15;
    float bi = b5s[ch];
    float s = 0.f, qq = 0.f;
#pragma unroll
    for (int r = 0; r < 4; ++r) {
      float v = ac[r] + bi;
      s += v; qq += v * v;
      ybf[w * 16 + q * 4 + r][ch] = f2bf(v);
    }
    const int g0 = (nt * 16) / 12;
    const int g1i = (nt * 16 + 15) / 12;
    const int cut = g1i * 12 - nt * 16;
    if (l15 < cut) { sg[g0] += s; qg[g0] += qq; }
    else           { sg[g1i] += s; qg[g1i] += qq; }
  }
#pragma unroll
  for (int g = 0; g < 8; ++g) {
#pragma unroll
    for (int off = 1; off < 64; off <<= 1) {
      sg[g] += __shfl_xor(sg[g], off);
      qg[g] += __shfl_xor(qg[g], off);
    }
  }
  if (lane == 0) {
#pragma unroll
    for (int g = 0; g < 8; ++g) {
      atomicAdd(&red[2 * g + 0], sg[g]);
      atomicAdd(&red[2 * g + 1], qg[g]);
    }
  }
  __syncthreads();
  unsigned* z5u = (unsigned*)z5bf;
  for (int idx = t; idx < 32 * 48; idx += 128) {
    int ptl = idx / 48, pr = idx - ptl * 48;
    z5u[(size_t)(p0 + ptl) * 48 + pr] = *(const unsigned*)&ybf[ptl][pr * 2];
  }
  if (t < 16) atomicAdd(&st5[b * 16 + t], red[t]);
}

// ------- K_post3 (f32, LDS weights): GN5+relu -> conv6 -> L2-norm -> out ---
__global__ __launch_bounds__(128) void k_post3(
    const unsigned short* __restrict__ z5bf, const float* __restrict__ st5,
    const float* __restrict__ g5, const float* __restrict__ be5,
    const float* __restrict__ w6, const float* __restrict__ b6,
    float* __restrict__ out) {
  __shared__ float y[32][100];        // f32 activations; reused as zs
  __shared__ float w6s[96][96];
  __shared__ float A5s[96], B5s[96], b6s[96];
  __shared__ float inv[32];
  const int t = threadIdx.x;
  const int ptl = t & 31, grp = t >> 5;
  const int p0 = blockIdx.x << 5;
  const int b = p0 >> 11;

  if (t < 96) {   // fused fin5 (count = 2048*12)
    int g = t / 12;
    float s = st5[b * 16 + 2 * g], qq = st5[b * 16 + 2 * g + 1];
    float mean = s * (1.0f / 24576.0f);
    float var  = qq * (1.0f / 24576.0f) - mean * mean;
    float r    = 1.0f / sqrtf(var + 1e-5f);
    float a    = g5[t] * r;
    A5s[t] = a; B5s[t] = be5[t] - mean * a; b6s[t] = b6[t];
  }
  for (int idx = t; idx < 9216; idx += 128)
    w6s[idx / 96][idx % 96] = w6[idx];
  __syncthreads();

  const unsigned* z5u = (const unsigned*)z5bf;
  for (int idx = t; idx < 32 * 48; idx += 128) {
    int pl = idx / 48, pr = idx - pl * 48;
    unsigned v = z5u[(size_t)(p0 + pl) * 48 + pr];
    int ch = pr * 2;
    float x0 = A5s[ch] * bf2f((unsigned short)(v & 0xffff)) + B5s[ch];
    float x1 = A5s[ch + 1] * bf2f((unsigned short)(v >> 16)) + B5s[ch + 1];
    y[pl][ch]     = x0 > 0.f ? x0 : 0.f;
    y[pl][ch + 1] = x1 > 0.f ? x1 : 0.f;
  }
  __syncthreads();

  const int ob = grp * 24;
  float z[24];
#pragma unroll
  for (int kb = 0; kb < 3; ++kb) {
    float a[8];
#pragma unroll
    for (int k = 0; k < 8; ++k) a[k] = b6s[ob + kb * 8 + k];
    for (int c4 = 0; c4 < 24; ++c4) {
      float4 xv = *(const float4*)&y[ptl][c4 * 4];
#pragma unroll
      for (int k = 0; k < 8; ++k) {
        const float* wr = &w6s[ob + kb * 8 + k][c4 * 4];
        a[k] += wr[0] * xv.x + wr[1] * xv.y + wr[2] * xv.z + wr[3] * xv.w;
      }
    }
#pragma unroll
    for (int k = 0; k < 8; ++k) z[kb * 8 + k] = a[k];
  }
  __syncthreads();   // all reads of y done -> reuse as zs
#pragma unroll
  for (int jj = 0; jj < 24; ++jj) y[ptl][ob + jj] = z[jj];
  __syncthreads();
  if (t < 32) {
    float ss = 0.f;
#pragma unroll
    for (int c = 0; c < 96; ++c) { float v = y[t][c]; ss += v * v; }
    float nf = (ss < 1e-20f) ? 0.0f : sqrtf(ss);
    inv[t] = 1.0f / nf;
  }
  __syncthreads();
  for (int idx = t; idx < 32 * 96; idx += 128) {
    int pl = idx / 96, ch = idx - pl * 96;
    out[(size_t)(p0 + pl) * 96 + ch] = y[pl][ch] * inv[pl];
  }
}

// --------------------------------------------------------------- launch ----
extern "C" void kernel_launch(void* const* d_in, const int* in_sizes, int n_in,
                              void* d_out, int out_size, void* d_ws, size_t ws_size,
                              hipStream_t stream) {
  (void)in_sizes; (void)n_in; (void)out_size; (void)ws_size;
  const float* xyz = (const float*)d_in[0];
  const float* nrm = (const float*)d_in[1];
  const float* w1 = (const float*)d_in[2];  const float* b1 = (const float*)d_in[3];
  const float* g1 = (const float*)d_in[4];  const float* be1 = (const float*)d_in[5];
  const float* w2 = (const float*)d_in[6];  const float* b2 = (const float*)d_in[7];
  const float* g2 = (const float*)d_in[8];  const float* be2 = (const float*)d_in[9];
  const float* w3 = (const float*)d_in[10]; const float* b3 = (const float*)d_in[11];
  const float* g3 = (const float*)d_in[12]; const float* be3 = (const float*)d_in[13];
  const float* w4 = (const float*)d_in[14]; const float* b4 = (const float*)d_in[15];
  const float* g4 = (const float*)d_in[16]; const float* be4 = (const float*)d_in[17];
  const float* w5 = (const float*)d_in[18]; const float* b5 = (const float*)d_in[19];
  const float* g5 = (const float*)d_in[20]; const float* be5 = (const float*)d_in[21];
  const float* w6 = (const float*)d_in[22]; const float* b6 = (const float*)d_in[23];

  float* ws = (float*)d_ws;
  unsigned short* fused = (unsigned short*)ws;   // 10,485,760 ushorts = 5,242,880 f
  unsigned short* zmxbf = (unsigned short*)(ws + 5242880);   // 3,145,728 ushorts
  unsigned short* zmnbf = zmxbf + 3145728;                   // 3,145,728 ushorts
  float* st1 = ws + 5242880 + 3145728;  //  128 each (after 2x1,572,864 f)
  float* st3 = st1 + 128;
  float* st4 = st3 + 128;
  float* st5 = st4 + 128;
  float* A2 = st5 + 128;  float* B2 = A2 + 768;
  float* wbuf = B2 + 768;               // bf16 frags: 86,016 ushorts = 43,008 f
  unsigned short* wh1 = (unsigned short*)wbuf;   //  3072
  unsigned short* wh2 = wh1 + 3072;              //  9216
  unsigned short* wh3 = wh2 + 9216;              // 18432
  unsigned short* wh4 = wh3 + 18432;             // 36864
  unsigned short* wh5 = wh4 + 36864;             // 18432
  float* G = wbuf + 43008;              // 8 x 12544 floats
  unsigned short* z4bf = (unsigned short*)(G + 100352);   // 3,145,728 ushorts
  unsigned short* z5bf = z4bf + 3145728;                  // 1,572,864 ushorts

  hipMemsetAsync(st1, 0, 4 * 128 * sizeof(float), stream);
  hipMemsetAsync(G, 0, 8 * 12544 * sizeof(float), stream);

  k_wprep <<<336, 256, 0, stream>>>(w1, w2, w3, w4, w5, wh1, wh2, wh3, wh4, wh5);
  k_feat  <<<4096, 256, 0, stream>>>(xyz, nrm, w1, b1, fused, st1);
  k_gram  <<<512, 256, 0, stream>>>(fused, wh1, b1, st1, g1, be1, G);
  k_fin2  <<<8, 384, 0, stream>>>(G, w2, b2, g2, be2, A2, B2);
  k_main  <<<4096, 256, 0, stream>>>(fused, b1, st1, g1, be1, wh1, wh2, b2, A2, B2,
                                     wh3, b3, zmxbf, zmnbf, st3);
  k_post1 <<<512, 128, 0, stream>>>(zmxbf, zmnbf, st3, g3, be3, wh4, b4, z4bf, st4);
  k_post2 <<<512, 128, 0, stream>>>(z4bf, st4, g4, be4, wh5, b5, z5bf, st5);
  k_post3 <<<512, 128, 0, stream>>>(z5bf, st5, g5, be5, w6, b6, (float*)d_out);
}